// Round 6
// baseline (257777.905 us; speedup 1.0000x reference)
//
#include <hip/hip_runtime.h>
#include <math.h>
#include <stdint.h>

#define NN 2048
#define NE 65536
#define ND 5
#define DMX 256
#define MAXB 12288
#define MAXRUN 2048
#define BIN_H 0.22f
#define NUDGE 2e-3f
#define THRG 0.5f

typedef float v2f __attribute__((ext_vector_type(2)));

// ============================ device helpers ============================
__device__ __forceinline__ float wredSum(float v){
#pragma unroll
  for (int o=32;o>0;o>>=1) v += __shfl_down(v,o,64);
  return v;
}
__device__ __forceinline__ float wredMin(float v){
#pragma unroll
  for (int o=32;o>0;o>>=1) v = fminf(v,__shfl_down(v,o,64));
  return v;
}
__device__ __forceinline__ float wredMax(float v){
#pragma unroll
  for (int o=32;o>0;o>>=1) v = fmaxf(v,__shfl_down(v,o,64));
  return v;
}
__device__ __forceinline__ uint32_t encF(float f){
  uint32_t u = __float_as_uint(f);
  return (u & 0x80000000u) ? ~u : (u | 0x80000000u);
}
__device__ __forceinline__ float decF(uint32_t u){
  return (u & 0x80000000u) ? __uint_as_float(u ^ 0x80000000u) : __uint_as_float(~u);
}

template<int BLK>
__device__ float bredSum(float v, float* red){
  v = wredSum(v);
  const int w = threadIdx.x >> 6;
  if ((threadIdx.x & 63) == 0) red[w] = v;
  __syncthreads();
  if (threadIdx.x == 0){
    float s = 0.f;
#pragma unroll
    for (int i=0;i<BLK/64;i++) s += red[i];
    red[0] = s;
  }
  __syncthreads();
  float r = red[0];
  __syncthreads();
  return r;
}

// ============================ nu(t) evaluation ============================
// nu(t) = #{eig(L) < t} = #{a_i < t} + n_-( I - X^T diag(1/(a-t)) X )
// Gram: packed-fp32 (v_pk_fma) 8x8 register tiles.
// Inertia: panel-8 blocked LDL^T — wave0 factors panel wave-synchronously,
// one parallel rank-8 trailing update, 2 barriers/panel.
template<int D, int BLK>
__device__ int evalNu(const float* __restrict__ xn, const float* __restrict__ a,
                      float t0, float dlt,
                      float* M, float* Pt, float* red, float* wrow,
                      float* scal, float* tOut)
{
  const int tid = threadIdx.x;
  constexpr int NTB = D/8;
  constexpr int NT  = NTB*(NTB+1)/2;
  constexpr int XS  = D + 4;   // padded staging stride
  constexpr int PS  = 12;      // Pt stride: 48B -> 16B-aligned, bank-spread

  // ---- phase 1a: nudge t away from poles a_i ----
  float md = 1e30f;
  for (int i=tid;i<NN;i+=BLK) md = fminf(md, fabsf(a[i]-t0));
  md = wredMin(md);
  if ((tid & 63) == 0) red[tid>>6] = md;
  __syncthreads();
  if (tid == 0){
    float m2 = 1e30f;
    for (int i=0;i<BLK/64;i++) m2 = fminf(m2, red[i]);
    scal[1] = (m2 < 1e-3f) ? (t0 + dlt) : t0;
  }
  __syncthreads();
  const float t = scal[1];
  __syncthreads();

  // ---- phase 1b: count a_i < t ----
  float c = 0.f;
  for (int i=tid;i<NN;i+=BLK) c += (a[i] < t) ? 1.f : 0.f;
  float cnt = bredSum<BLK>(c, red);

  // ---- phase 2: G = sum_i w_i x_i x_i^T, packed-fp32 8x8 tiles ----
  int ta = 0, tb = 0;
  if (tid < NT){
    int rem = tid, row = 0;
    while (rem >= NTB - row){ rem -= NTB - row; row++; }
    ta = row; tb = row + rem;
  }
  v2f acc2[32];
#pragma unroll
  for (int i=0;i<32;i++) acc2[i] = (v2f){0.f, 0.f};

  float* xt = M;  // overlay: padded x-tile staging lives where M will go
  for (int i0=0;i0<NN;i0+=16){
    __syncthreads();
    const float4* src = reinterpret_cast<const float4*>(xn + (size_t)i0*D);
    float4* dstv = reinterpret_cast<float4*>(xt);
    for (int l = tid; l < 16*(D/4); l += BLK){
      const int row = l/(D/4), c4 = l%(D/4);
      dstv[row*(XS/4) + c4] = src[l];
    }
    if (tid < 16){
      float den = a[i0+tid] - t;
      if (fabsf(den) < 1e-5f) den = (den < 0.f) ? -1e-5f : 1e-5f;
      wrow[tid] = 1.0f/den;
    }
    __syncthreads();
    if (tid < NT){
#pragma unroll 4
      for (int rs=0;rs<16;rs++){
        const int rr = (rs + tid) & 15;     // lane stagger: spread LDS banks
        const float* xr = xt + rr*XS;
        const float wv = wrow[rr];
        float4 A0 = reinterpret_cast<const float4*>(xr + ta*8)[0];
        float4 A1 = reinterpret_cast<const float4*>(xr + ta*8)[1];
        float4 B0 = reinterpret_cast<const float4*>(xr + tb*8)[0];
        float4 B1 = reinterpret_cast<const float4*>(xr + tb*8)[1];
        float xa[8] = {A0.x*wv,A0.y*wv,A0.z*wv,A0.w*wv,A1.x*wv,A1.y*wv,A1.z*wv,A1.w*wv};
        v2f xb2[4] = {{B0.x,B0.y},{B0.z,B0.w},{B1.x,B1.y},{B1.z,B1.w}};
#pragma unroll
        for (int j=0;j<8;j++){
          const v2f xaj = {xa[j], xa[j]};
#pragma unroll
          for (int m=0;m<4;m++)
            acc2[j*4+m] = __builtin_elementwise_fma(xaj, xb2[m], acc2[j*4+m]);
        }
      }
    }
  }
  __syncthreads();

  // ---- phase 2b: M = I - G, packed upper triangle (row-major) ----
  if (tid < NT){
#pragma unroll
    for (int j=0;j<8;j++){
      int aa = ta*8+j;
      int offa = aa*D - (aa*(aa-1))/2;
#pragma unroll
      for (int mm=0;mm<8;mm++){
        int bb = tb*8+mm;
        if (aa <= bb) M[offa + (bb-aa)] = ((aa==bb)?1.f:0.f) - acc2[j*4+(mm>>1)][mm&1];
      }
    }
  }

  // ---- phase 3: panel-8 blocked LDL^T ----
  int neg = 0;   // meaningful on wave0 (uniform there)
  for (int k0=0; k0<D; k0+=8){
    const int k1 = k0+8;
    __syncthreads();    // prev trailing / phase-2b visible
    if (tid < 64){
      for (int q=k0; q<k1; q++){
        const int offq = q*D - (q*(q-1))/2;
        for (int p=k0; p<q; p++){
          const float cpq = M[p*D - (p*(p-1))/2 + (q-p)];
          const int pc = p - k0;
          for (int j=q+tid; j<D; j+=64)
            M[offq + (j-q)] = fmaf(-cpq, Pt[j*PS + pc], M[offq + (j-q)]);
        }
        __asm__ __volatile__("s_waitcnt lgkmcnt(0)" ::: "memory");
        const float dq = M[offq];
        if (dq < 0.f) neg++;
        float dd = dq;
        if (fabsf(dd) < 1e-8f) dd = (dd<0.f)?-1e-8f:1e-8f;
        const float invd = 1.0f/dd;
        const int qc = q - k0;
        for (int j=q+1+tid; j<D; j+=64)
          Pt[j*PS + qc] = M[offq + (j-q)] * invd;
        __asm__ __volatile__("s_waitcnt lgkmcnt(0)" ::: "memory");
      }
    }
    __syncthreads();    // publish panel rows + Pt
    if (k1 < D){
      constexpr int G = BLK/4;
      const int grp = tid / G, sub = tid % G;
      for (int i0=k1; i0<D; i0+=4){
        const int i = i0 + grp;          // D-k1 multiple of 8 -> valid
        float cq[8];
#pragma unroll
        for (int q=0;q<8;q++){
          const int g = k0+q;
          cq[q] = M[g*D - (g*(g-1))/2 + (i-g)];
        }
        const int offi = i*D - (i*(i-1))/2;
        for (int j=i+sub; j<D; j+=G){
          const float4 p0 = *reinterpret_cast<const float4*>(&Pt[j*PS + 0]);
          const float4 p1 = *reinterpret_cast<const float4*>(&Pt[j*PS + 4]);
          float v = M[offi + (j-i)];
          v = fmaf(-cq[0],p0.x,v); v = fmaf(-cq[1],p0.y,v);
          v = fmaf(-cq[2],p0.z,v); v = fmaf(-cq[3],p0.w,v);
          v = fmaf(-cq[4],p1.x,v); v = fmaf(-cq[5],p1.y,v);
          v = fmaf(-cq[6],p1.z,v); v = fmaf(-cq[7],p1.w,v);
          M[offi + (j-i)] = v;
        }
      }
    }
  }
  if (tid == 0) ((int*)scal)[5] = neg;
  __syncthreads();
  const int negAll = ((int*)scal)[5];
  __syncthreads();

  *tOut = t;
  return negAll + (int)(cnt + 0.5f);
}

#define SMEM_D(D) (((D)*((D)+1)/2 + 12*(D) + 64)*4)

// single-level uniform grid eval, h <= 0.22 (empty-bin guarantee: 2h+2*nudge < 0.5)
template<int D, int BLK, int WPE>
__global__ __launch_bounds__(BLK,WPE) void k_eval(const float* __restrict__ xnb,
    const float* __restrict__ ab, const float* __restrict__ ctrlF,
    const int* __restrict__ ctrlI, int* __restrict__ nu, float* __restrict__ tus)
{
  const int dim = blockIdx.y;
  const int b = blockIdx.x;
  if (b > ctrlI[dim*8+0]) return;
  extern __shared__ float smem[];
  constexpr int TRI = D*(D+1)/2;
  float* M = smem; float* Pt = M+TRI; float* red = Pt + 12*D;
  float* wrow = red+16; float* scal = wrow+16;
  const float lo = ctrlF[dim*8+0], h = ctrlF[dim*8+1];
  float tU;
  int v = evalNu<D,BLK>(xnb + (size_t)dim*NN*D, ab + dim*NN, lo + h*b, NUDGE,
                        M,Pt,red,wrow,scal,&tU);
  if (threadIdx.x == 0){ nu[(size_t)dim*(MAXB+1)+b] = v; tus[(size_t)dim*(MAXB+1)+b] = tU; }
}

// one-shot 16-section probes: 16 points per side per ambiguous run, all parallel
template<int D, int BLK, int WPE>
__global__ __launch_bounds__(BLK,WPE) void k_probe(const float* __restrict__ xnb,
    const float* __restrict__ ab, const int* __restrict__ ctrlI,
    const int* __restrict__ runP, const float* __restrict__ runB,
    int* __restrict__ nuP, float* __restrict__ tP)
{
  const int dim = blockIdx.y;
  const int r = blockIdx.x >> 5;
  int nr = ctrlI[dim*8+1]; if (nr > MAXRUN) nr = MAXRUN;
  if (r >= nr) return;
  const int side = (blockIdx.x >> 4) & 1;
  const int i = blockIdx.x & 15;
  extern __shared__ float smem[];
  constexpr int TRI = D*(D+1)/2;
  float* M = smem; float* Pt = M+TRI; float* red = Pt + 12*D;
  float* wrow = red+16; float* scal = wrow+16;
  const float* rb = runB + (size_t)(dim*MAXRUN + r)*4;
  const float lo = rb[side*2+0], hi = rb[side*2+1];
  const float t0 = lo + (hi - lo)*(float)(i+1)*(1.0f/17.0f);
  const float dlt = fminf(NUDGE, (hi-lo)*0.02f);
  float tU;
  int v = evalNu<D,BLK>(xnb + (size_t)dim*NN*D, ab + dim*NN, t0, dlt,
                        M,Pt,red,wrow,scal,&tU);
  if (threadIdx.x == 0){
    const size_t o = (((size_t)dim*MAXRUN + r)*2 + side)*16 + i;
    nuP[o] = v; tP[o] = tU;
  }
}

__global__ void k_decide(const int* __restrict__ ctrlI, const int* __restrict__ runP,
                         const float* __restrict__ runB, const int* __restrict__ nuP,
                         const float* __restrict__ tP, int* __restrict__ bnd){
  const int dim = blockIdx.x;
  int nr = ctrlI[dim*8+1]; if (nr > MAXRUN) nr = MAXRUN;
  for (int r = threadIdx.x; r < nr; r += blockDim.x){
    const int p = runP[dim*MAXRUN + r];
    const float* rb = runB + (size_t)(dim*MAXRUN + r)*4;
    float lam[2];
    for (int side=0; side<2; side++){
      const int rank = p + side;   // nu(t) >= rank  <=>  lam_rank < t
      const size_t o = (((size_t)dim*MAXRUN + r)*2 + side)*16;
      float prev = rb[side*2+0];
      bool found = false; float l = 0.f;
      for (int i=0;i<16;i++){
        const float ti = tP[o+i];
        if (nuP[o+i] >= rank){ l = 0.5f*(prev + ti); found = true; break; }
        prev = ti;
      }
      if (!found) l = 0.5f*(prev + rb[side*2+1]);
      lam[side] = l;
    }
    if (lam[1] - lam[0] > THRG) bnd[dim*NN + p - 1] = 1;
  }
}

// parallel run detection on the uniform grid
__global__ void k_runs(const int* __restrict__ nu, const float* __restrict__ tus,
                       int* ctrlI, int* __restrict__ runP, float* __restrict__ runB,
                       int* __restrict__ bnd){
  const int dim = blockIdx.y;
  const int b1 = blockIdx.x*256 + threadIdx.x;
  const int nb = ctrlI[dim*8+0];
  if (b1 >= nb) return;
  const int* nv = nu + (size_t)dim*(MAXB+1);
  const float* tu = tus + (size_t)dim*(MAXB+1);
  if (nv[b1+1] != nv[b1]) return;              // not an empty bin
  if (b1 > 0 && nv[b1-1] == nv[b1]) return;    // not the run start
  int j2 = b1;
  while (j2+1 < nb && nv[j2+2] == nv[j2+1]) j2++;
  const int p = nv[b1];
  if (p < 1 || p > NN-1 || b1 < 1 || j2 > nb-2) return;
  const float gmin = tu[j2+1] - tu[b1];
  const float gmax = tu[j2+2] - tu[b1-1];
  if (gmin > THRG){ bnd[dim*NN + p-1] = 1; return; }
  if (gmax > THRG){
    const int slot = atomicAdd(&ctrlI[dim*8+1], 1);
    if (slot < MAXRUN){
      runP[dim*MAXRUN + slot] = p;
      float* rb = runB + (size_t)(dim*MAXRUN + slot)*4;
      rb[0]=tu[b1-1]; rb[1]=tu[b1]; rb[2]=tu[j2+1]; rb[3]=tu[j2+2];
    }
  }
}

// ============================ power iteration for lambda_min(L) ============
template<int D>
__global__ __launch_bounds__(256) void k_power(const float* __restrict__ xnb,
    const float* __restrict__ ab, const uint32_t* __restrict__ ctrlU,
    float* __restrict__ thB)
{
  const int dim = blockIdx.x, tid = threadIdx.x;
  const float* x = xnb + (size_t)dim*NN*D;
  const float* a = ab + dim*NN;
  __shared__ float v[NN];
  __shared__ float z[DMX];
  __shared__ float red[4];
  __shared__ float redR[4];
  __shared__ float sc[2];
  const float amax = decF(ctrlU[dim*8+1]);
  for (int i=tid;i<NN;i+=256){
    uint32_t hsh = (uint32_t)i*2654435761u;
    v[i] = 1.0f + 2e-4f*(float)(hsh>>20);
  }
  __syncthreads();
  float theta = 0.f;
  for (int it=0; it<33; it++){
    if (tid < D){
      float s = 0.f;
      for (int i=0;i<NN;i++) s = fmaf(x[(size_t)i*D+tid], v[i], s);
      z[tid] = s;
    }
    __syncthreads();
    const int grp = tid>>2, sub = tid&3;
    float n2 = 0.f, ray = 0.f;
    const float4* z4 = reinterpret_cast<const float4*>(z);
    for (int p=0;p<NN/64;p++){
      const int i = p*64 + grp;
      const float4* xr = reinterpret_cast<const float4*>(x + (size_t)i*D);
      float dot = 0.f;
      for (int c=sub;c<D/4;c+=4){
        float4 xx = xr[c]; float4 zz = z4[c];
        dot = fmaf(xx.x,zz.x, fmaf(xx.y,zz.y, fmaf(xx.z,zz.z, fmaf(xx.w,zz.w, dot))));
      }
      dot += __shfl_xor(dot,1,64);
      dot += __shfl_xor(dot,2,64);
      const float vi = v[i];
      const float y = (amax - a[i])*vi + dot;
      if (sub==0){ n2 += y*y; ray += vi*y; v[i] = y; }
    }
    __syncthreads();
    n2 = wredSum(n2); ray = wredSum(ray);
    if ((tid&63)==0){ red[tid>>6] = n2; redR[tid>>6] = ray; }
    __syncthreads();
    if (tid==0){
      float s = red[0]+red[1]+red[2]+red[3];
      float r = redR[0]+redR[1]+redR[2]+redR[3];
      sc[0] = rsqrtf(fmaxf(s,1e-30f));
      sc[1] = r;
    }
    __syncthreads();
    theta = sc[1];
    const float inv = sc[0];
    for (int i=tid;i<NN;i+=256) v[i] *= inv;
    __syncthreads();
  }
  if (tid==0) thB[dim] = theta;
}

// ============================ graph / GCN kernels ============================
__global__ void k_init(float* deg, int* cur){
  const int dim = blockIdx.x;
  for (int i=threadIdx.x;i<NN;i+=blockDim.x){ deg[dim*NN+i] = 1.0f; cur[dim*NN+i] = 0; }
}
__global__ void k_count(const int* __restrict__ eidx, const float* __restrict__ ew,
                        float* deg, int* cur){
  const int idx = blockIdx.x*256 + threadIdx.x;
  if (idx >= ND*NE) return;
  const int dim = idx / NE, e = idx % NE;
  const int dst = eidx[(size_t)dim*2*NE + NE + e];
  atomicAdd(&cur[dim*NN + dst], 1);
  atomicAdd(&deg[dim*NN + dst], ew[(size_t)dim*NE + e]);
}
__global__ void k_prefix(int* cur, int* base){
  const int dim = blockIdx.x;
  if (threadIdx.x) return;
  int* b = base + dim*(NN+1);
  int* cc = cur + dim*NN;
  int run = 0; b[0] = 0;
  for (int i=0;i<NN;i++){ int cnt = cc[i]; cc[i] = run; b[i+1] = run + cnt; run += cnt; }
}
__global__ void k_fill_csr(const int* __restrict__ eidx, const float* __restrict__ ew,
                       const float* __restrict__ deg, int* cur, int* psrc, float* coef){
  const int idx = blockIdx.x*256 + threadIdx.x;
  if (idx >= ND*NE) return;
  const int dim = idx / NE, e = idx % NE;
  const int src = eidx[(size_t)dim*2*NE + e];
  const int dst = eidx[(size_t)dim*2*NE + NE + e];
  const int slot = atomicAdd(&cur[dim*NN + dst], 1);
  psrc[(size_t)dim*NE + slot] = src;
  const float ds = deg[dim*NN + src], dd = deg[dim*NN + dst];
  coef[(size_t)dim*NE + slot] = ew[(size_t)dim*NE + e] * (1.0f/sqrtf(ds)) * (1.0f/sqrtf(dd));
}
__global__ void k_selfw(const float* deg, float* sw){
  const int idx = blockIdx.x*256 + threadIdx.x;
  if (idx < ND*NN) sw[idx] = 1.0f/deg[idx];
}

// generic tiled GEMM: C[M,P] = A[M,K] @ W[K,P] (+bias). grid z = dim axis.
__global__ __launch_bounds__(256) void k_gemm(const float* __restrict__ A, long long aStr,
    const float* __restrict__ W, long long wStr,
    const float* __restrict__ bias, long long bStr,
    float* __restrict__ C, long long cStr, int M, int K, int P)
{
  const int dim = blockIdx.z;
  A += (size_t)dim*aStr; W += (size_t)dim*wStr; C += (size_t)dim*cStr;
  if (bias) bias += (size_t)dim*bStr;
  __shared__ float As[64][17];
  __shared__ float Bs[16][68];
  const int tid = threadIdx.x;
  const int tx = tid % 16, ty = tid / 16;
  const int m0 = blockIdx.y*64, p0 = blockIdx.x*64;
  float acc[4][4] = {};
  for (int k0=0;k0<K;k0+=16){
    __syncthreads();
    { int r = tid/4, c4 = (tid%4)*4;
      float4 v = *reinterpret_cast<const float4*>(A + (size_t)(m0+r)*K + k0 + c4);
      As[r][c4]=v.x; As[r][c4+1]=v.y; As[r][c4+2]=v.z; As[r][c4+3]=v.w; }
    { int r = tid/16, c4 = (tid%16)*4;
      float4 v = *reinterpret_cast<const float4*>(W + (size_t)(k0+r)*P + p0 + c4);
      Bs[r][c4]=v.x; Bs[r][c4+1]=v.y; Bs[r][c4+2]=v.z; Bs[r][c4+3]=v.w; }
    __syncthreads();
#pragma unroll
    for (int kk=0;kk<16;kk++){
      float a0=As[ty*4+0][kk], a1=As[ty*4+1][kk], a2=As[ty*4+2][kk], a3=As[ty*4+3][kk];
      float b0=Bs[kk][tx*4+0], b1=Bs[kk][tx*4+1], b2=Bs[kk][tx*4+2], b3=Bs[kk][tx*4+3];
      acc[0][0]=fmaf(a0,b0,acc[0][0]); acc[0][1]=fmaf(a0,b1,acc[0][1]);
      acc[0][2]=fmaf(a0,b2,acc[0][2]); acc[0][3]=fmaf(a0,b3,acc[0][3]);
      acc[1][0]=fmaf(a1,b0,acc[1][0]); acc[1][1]=fmaf(a1,b1,acc[1][1]);
      acc[1][2]=fmaf(a1,b2,acc[1][2]); acc[1][3]=fmaf(a1,b3,acc[1][3]);
      acc[2][0]=fmaf(a2,b0,acc[2][0]); acc[2][1]=fmaf(a2,b1,acc[2][1]);
      acc[2][2]=fmaf(a2,b2,acc[2][2]); acc[2][3]=fmaf(a2,b3,acc[2][3]);
      acc[3][0]=fmaf(a3,b0,acc[3][0]); acc[3][1]=fmaf(a3,b1,acc[3][1]);
      acc[3][2]=fmaf(a3,b2,acc[3][2]); acc[3][3]=fmaf(a3,b3,acc[3][3]);
    }
  }
  for (int i=0;i<4;i++){
    for (int j=0;j<4;j++){
      const int pp = p0 + tx*4 + j;
      float v = acc[i][j];
      if (bias) v += bias[pp];
      C[(size_t)(m0+ty*4+i)*P + pp] = v;
    }
  }
}

__global__ void k_agg(const float* __restrict__ h, float* __restrict__ g,
                      const float* __restrict__ convb, const int* __restrict__ base,
                      const int* __restrict__ psrc, const float* __restrict__ coef,
                      const float* __restrict__ selfw, int co)
{
  const int i = blockIdx.x, dim = blockIdx.y, c = threadIdx.x;
  const float* hD = h + (size_t)dim*NN*co;
  const int s = base[dim*(NN+1)+i], e = base[dim*(NN+1)+i+1];
  const int* ps = psrc + (size_t)dim*NE;
  const float* cf = coef + (size_t)dim*NE;
  float acc = 0.f;
  for (int q=s;q<e;q++) acc += cf[q]*hD[(size_t)ps[q]*co + c];
  g[((size_t)dim*NN+i)*co + c] = acc + hD[(size_t)i*co + c]*selfw[dim*NN+i] + convb[dim*co + c];
}

__global__ void k_rownorm(const float* __restrict__ g, float* __restrict__ xn, int co){
  const int i = blockIdx.x, dim = blockIdx.y;
  const float* gr = g + ((size_t)dim*NN+i)*co;
  float* xr = xn + ((size_t)dim*NN+i)*co;
  float p = 0.f;
  for (int c=threadIdx.x;c<co;c+=256){ float v = gr[c]; p += v*v; }
  __shared__ float red[4];
  p = wredSum(p);
  if ((threadIdx.x&63)==0) red[threadIdx.x>>6] = p;
  __syncthreads();
  if (threadIdx.x==0) red[0] = red[0]+red[1]+red[2]+red[3];
  __syncthreads();
  const float inv = 1.0f/(sqrtf(red[0]) + 1e-8f);
  for (int c=threadIdx.x;c<co;c+=256) xr[c] = gr[c]*inv;
}

__global__ void k_colsum(const float* __restrict__ xn, float* __restrict__ sb, int co){
  const int c = blockIdx.x*64 + threadIdx.x;
  const int dim = blockIdx.y;
  const float* x = xn + (size_t)dim*NN*co;
  float s = 0.f;
  for (int i=0;i<NN;i++) s += x[(size_t)i*co + c];
  sb[dim*DMX + c] = s;
}

__global__ void k_adot(const float* __restrict__ xn, const float* __restrict__ sb,
                       float* __restrict__ ab, uint32_t* ctrlU, int co){
  const int i = blockIdx.x, dim = blockIdx.y;
  const float* x = xn + ((size_t)dim*NN + i)*co;
  const float* s = sb + dim*DMX;
  float p = 0.f;
  for (int c=threadIdx.x;c<co;c+=128) p += x[c]*s[c];
  p = wredSum(p);
  __shared__ float red[2];
  if ((threadIdx.x&63)==0) red[threadIdx.x>>6] = p;
  __syncthreads();
  if (threadIdx.x==0){
    const float v = red[0] + red[1];
    ab[dim*NN+i] = v;
    const uint32_t e = encF(v);
    atomicMin(&ctrlU[dim*8+0], e);
    atomicMax(&ctrlU[dim*8+1], e);
  }
}

__global__ __launch_bounds__(256) void k_gramC(const float* __restrict__ xn,
                                               float* __restrict__ Cb, int co){
  const int dim = blockIdx.y;
  const int nbx = co/32;
  const int bx = blockIdx.x % nbx, by = blockIdx.x / nbx;
  const float* x = xn + (size_t)dim*NN*co;
  float* C = Cb + (size_t)dim*co*co;
  __shared__ float Xa[64][33];
  __shared__ float Xb[64][33];
  const int tid = threadIdx.x;
  const int ty = tid/16, tx = tid%16;
  float a00=0,a01=0,a10=0,a11=0;
  for (int i0=0;i0<NN;i0+=64){
    __syncthreads();
    for (int l=tid;l<512;l+=256){
      const int r = l/8, c4 = (l%8)*4;
      float4 va = *reinterpret_cast<const float4*>(x + (size_t)(i0+r)*co + by*32 + c4);
      Xa[r][c4]=va.x; Xa[r][c4+1]=va.y; Xa[r][c4+2]=va.z; Xa[r][c4+3]=va.w;
      float4 vb = *reinterpret_cast<const float4*>(x + (size_t)(i0+r)*co + bx*32 + c4);
      Xb[r][c4]=vb.x; Xb[r][c4+1]=vb.y; Xb[r][c4+2]=vb.z; Xb[r][c4+3]=vb.w;
    }
    __syncthreads();
#pragma unroll 8
    for (int r=0;r<64;r++){
      const float u0=Xa[r][ty*2], u1=Xa[r][ty*2+1], w0=Xb[r][tx*2], w1=Xb[r][tx*2+1];
      a00=fmaf(u0,w0,a00); a01=fmaf(u0,w1,a01); a10=fmaf(u1,w0,a10); a11=fmaf(u1,w1,a11);
    }
  }
  const int ca = by*32 + ty*2, cb = bx*32 + tx*2;
  C[(size_t)(ca+0)*co + cb+0]=a00; C[(size_t)(ca+0)*co + cb+1]=a01;
  C[(size_t)(ca+1)*co + cb+0]=a10; C[(size_t)(ca+1)*co + cb+1]=a11;
}

__global__ void k_layerinit(int* bnd, uint32_t* ctrlU, int* ctrlI){
  const int dim = blockIdx.x;
  for (int i=threadIdx.x;i<NN;i+=blockDim.x) bnd[dim*NN+i] = 0;
  if (threadIdx.x==0){
    ctrlU[dim*8+0] = 0xFFFFFFFFu;
    ctrlU[dim*8+1] = 0u;
    ctrlI[dim*8+1] = 0;
  }
}

// lo = max(amin - gersh(C), amax - theta - pad); uniform bins of width <= BIN_H
__global__ __launch_bounds__(256) void k_bounds(const float* __restrict__ Cb,
                         const uint32_t* ctrlU, const float* __restrict__ thB,
                         float* ctrlF, int* ctrlI, int co){
  const int dim = blockIdx.x, tid = threadIdx.x;
  const float* C = Cb + (size_t)dim*co*co;
  __shared__ float red[4];
  float rs = 0.f;
  if (tid < co){
    const float* row = C + (size_t)tid*co;
    for (int b=0;b<co;b++) rs += fabsf(row[b]);
  }
  float mx = wredMax(rs);
  if ((tid&63)==0) red[tid>>6] = mx;
  __syncthreads();
  if (tid==0){
    const float gersh = fmaxf(fmaxf(red[0],red[1]), fmaxf(red[2],red[3]));
    const float amin = decF(ctrlU[dim*8+0]);
    const float amax = decF(ctrlU[dim*8+1]);
    const float th = thB[dim];
    const float loG = amin - gersh;
    const float loP = amax - th - (0.02f*fabsf(th) + 0.5f);
    const float lo = fmaxf(loG, loP) - 0.05f;
    const float hi = amax + 0.1f;
    int nb = (int)ceilf((hi - lo)/BIN_H);
    if (nb > MAXB) nb = MAXB;
    if (nb < 8) nb = 8;
    ctrlF[dim*8+0] = lo;
    ctrlF[dim*8+1] = (hi - lo)/nb;
    ctrlI[dim*8+0] = nb;
  }
}

__global__ void k_flags(const int* __restrict__ bnd, int* flags, int* cstart, int* ctrlI){
  const int dim = blockIdx.x;
  if (threadIdx.x) return;
  const int* b = bnd + dim*NN;
  int* f = flags + dim*NN;
  int* cs = cstart + dim*(NN+1);
  int cur = 0; f[0] = 0; cs[0] = 0;
  for (int i=1;i<NN;i++){
    cur += b[i-1];
    f[i] = cur;
    if (b[i-1]) cs[cur] = i;
  }
  ctrlI[dim*8+2] = cur+1;
  cs[cur+1] = NN;
}

__global__ void k_cavg(const float* __restrict__ g, const int* __restrict__ cstart,
                       const int* __restrict__ ctrlI, float* __restrict__ cavg, int co){
  const int dim = blockIdx.y;
  const int nc = ctrlI[dim*8+2];
  const float* gD = g + (size_t)dim*NN*co;
  const int cc = threadIdx.x;
  for (int c = blockIdx.x; c < nc; c += gridDim.x){
    const int s = cstart[dim*(NN+1)+c], e = cstart[dim*(NN+1)+c+1];
    const float inv = 1.0f/(float)(e - s);
    if (cc < co){
      float acc = 0.f;
      for (int i=s;i<e;i++) acc += gD[(size_t)i*co + cc];
      cavg[((size_t)dim*NN + c)*co + cc] = acc*inv;
    }
  }
}

__global__ void k_clin(const float* __restrict__ cavg, const float* __restrict__ linW,
                       const float* __restrict__ linb, float* __restrict__ clin,
                       const int* __restrict__ ctrlI, int co){
  const int dim = blockIdx.y;
  const int nc = ctrlI[dim*8+2];
  __shared__ float row[DMX];
  const int tid = threadIdx.x;
  for (int c = blockIdx.x; c < nc; c += gridDim.x){
    const float* av = cavg + ((size_t)dim*NN + c)*co;
    __syncthreads();
    if (tid < co) row[tid] = av[tid];
    __syncthreads();
    if (tid < co){
      float s = linb[tid];
      for (int k=0;k<co;k++) s = fmaf(row[k], linW[(size_t)k*co + tid], s);
      clin[((size_t)dim*NN + c)*co + tid] = s;
    }
  }
}

__global__ void k_out(const float* __restrict__ fir, const float* __restrict__ clin,
                      const int* __restrict__ flags, const float* __restrict__ ksv,
                      float* __restrict__ out, int co){
  const int i = blockIdx.x, dim = blockIdx.y, c = threadIdx.x;
  const float kv = ksv[0];
  const int cls = flags[dim*NN+i];
  const float fv = fir[((size_t)dim*NN+i)*co + c];
  const float lv = clin[((size_t)dim*NN+cls)*co + c];
  const float o = 2.f*fv + kv*lv;
  out[((size_t)dim*NN+i)*co + c] = (o > 0.f) ? o : 0.f;
}

__global__ void k_final(const float* __restrict__ outL, const float* __restrict__ dimw,
                        float* __restrict__ o){
  const int i = blockIdx.x, c = threadIdx.x;
  float w[ND]; float ws = 0.f;
#pragma unroll
  for (int d=0;d<ND;d++){ w[d] = dimw[d]; ws += w[d]; }
  float v = 0.f;
#pragma unroll
  for (int d=0;d<ND;d++) v += (w[d]/ws) * outL[((size_t)d*NN + i)*128 + c];
  o[(size_t)i*128 + c] = v;
}

// ============================ host ============================
extern "C" void kernel_launch(void* const* d_in, const int* in_sizes, int n_in,
                              void* d_out, int out_size, void* d_ws, size_t ws_size,
                              hipStream_t stream)
{
  const float* dims_in[ND];
  for (int d=0;d<ND;d++) dims_in[d] = (const float*)d_in[d];
  const int*   eidx = (const int*)d_in[5];
  const float* ew   = (const float*)d_in[6];
  const float* convW[6]; const float* convb[6];
  for (int l=0;l<6;l++){ convW[l] = (const float*)d_in[8+2*l]; convb[l] = (const float*)d_in[9+2*l]; }
  const float* linW[6]; const float* linb[6];
  for (int l=0;l<6;l++){ linW[l] = (const float*)d_in[20+2*l]; linb[l] = (const float*)d_in[21+2*l]; }
  const float* ch1W = (const float*)d_in[32]; const float* ch1b = (const float*)d_in[33];
  const float* ch2W = (const float*)d_in[34]; const float* ch2b = (const float*)d_in[35];
  const float* dimw = (const float*)d_in[36]; const float* ksv = (const float*)d_in[37];

  // ---- carve workspace ----
  char* p = (char*)d_ws;
  auto take = [&](size_t bytes)->char*{
    char* r = p; p += (bytes + 255) & ~(size_t)255; return r;
  };
  int*   csr_base = (int*)  take((size_t)ND*(NN+1)*4);
  int*   csr_cur  = (int*)  take((size_t)ND*NN*4);
  int*   csr_psrc = (int*)  take((size_t)ND*NE*4);
  float* csr_coef = (float*)take((size_t)ND*NE*4);
  float* deg      = (float*)take((size_t)ND*NN*4);
  float* selfw    = (float*)take((size_t)ND*NN*4);
  float* gA   = (float*)take((size_t)ND*NN*DMX*4);
  float* gB   = (float*)take((size_t)ND*NN*DMX*4);
  float* outA = (float*)take((size_t)ND*NN*DMX*4);
  float* outB = (float*)take((size_t)ND*NN*DMX*4);
  float* hbuf = (float*)take((size_t)ND*NN*DMX*4);
  float* xnbuf= (float*)take((size_t)ND*NN*DMX*4);
  float* cavg = (float*)take((size_t)ND*NN*DMX*4);
  float* abuf = (float*)take((size_t)ND*NN*4);
  float* sbuf = (float*)take((size_t)ND*DMX*4);
  float* Cbuf = (float*)take((size_t)ND*DMX*DMX*4);
  int*   nuA  = (int*)  take((size_t)ND*(MAXB+1)*4);
  float* tusA = (float*)take((size_t)ND*(MAXB+1)*4);
  int*   runP = (int*)  take((size_t)ND*MAXRUN*4);
  float* runB = (float*)take((size_t)ND*MAXRUN*4*4);
  int*   nuP  = (int*)  take((size_t)ND*MAXRUN*2*16*4);
  float* tP   = (float*)take((size_t)ND*MAXRUN*2*16*4);
  int*   bnd  = (int*)  take((size_t)ND*NN*4);
  int*   flagsA=(int*)  take((size_t)ND*NN*4);
  int*   cstart=(int*)  take((size_t)ND*(NN+1)*4);
  float* ctrlF= (float*)take((size_t)ND*8*4);
  uint32_t* ctrlU = (uint32_t*)take((size_t)ND*8*4);
  int*   ctrlI= (int*)  take((size_t)ND*8*4);
  float* thB  = (float*)take((size_t)ND*4);
  (void)ws_size; (void)in_sizes; (void)n_in; (void)out_size;

  // ---- allow >64KB dynamic LDS for the D=256 eval kernels ----
  {
    void (*pe)(const float*,const float*,const float*,const int*,int*,float*) = k_eval<256,576,2>;
    hipFuncSetAttribute((const void*)pe, hipFuncAttributeMaxDynamicSharedMemorySize, SMEM_D(256));
    void (*pp)(const float*,const float*,const int*,const int*,const float*,int*,float*) = k_probe<256,576,2>;
    hipFuncSetAttribute((const void*)pp, hipFuncAttributeMaxDynamicSharedMemorySize, SMEM_D(256));
  }

  // ---- CSR setup (edges fixed across layers) ----
  k_init<<<ND, 256, 0, stream>>>(deg, csr_cur);
  k_count<<<(ND*NE+255)/256, 256, 0, stream>>>(eidx, ew, deg, csr_cur);
  k_prefix<<<ND, 64, 0, stream>>>(csr_cur, csr_base);
  k_fill_csr<<<(ND*NE+255)/256, 256, 0, stream>>>(eidx, ew, deg, csr_cur, csr_psrc, csr_coef);
  k_selfw<<<(ND*NN+255)/256, 256, 0, stream>>>(deg, selfw);

  float* gbufs[2] = {gA, gB};
  float* obufs[2] = {outA, outB};
  const float* gPrev = nullptr;
  const float* oPrev = nullptr;

  for (int l=0;l<6;l++){
    const int co = (l==0) ? 256 : 128;
    const int ci = (l==0) ? 512 : ((l==1) ? 256 : 128);
    float* gCur = gbufs[l&1];
    float* oCur = obufs[l&1];

    if (l==0){
      for (int d=0;d<ND;d++)
        k_gemm<<<dim3(256/64, NN/64, 1), 256, 0, stream>>>(
          dims_in[d], 0, convW[0] + (size_t)d*512*256, 0, nullptr, 0,
          hbuf + (size_t)d*NN*256, 0, NN, 512, 256);
    } else {
      k_gemm<<<dim3(co/64, NN/64, ND), 256, 0, stream>>>(
        gPrev, (long long)NN*ci, convW[l], (long long)ci*co, nullptr, 0,
        hbuf, (long long)NN*co, NN, ci, co);
    }

    k_layerinit<<<ND, 256, 0, stream>>>(bnd, ctrlU, ctrlI);
    k_agg<<<dim3(NN, ND), co, 0, stream>>>(hbuf, gCur, convb[l], csr_base, csr_psrc,
                                           csr_coef, selfw, co);
    k_rownorm<<<dim3(NN, ND), 256, 0, stream>>>(gCur, xnbuf, co);
    k_colsum<<<dim3(co/64, ND), 64, 0, stream>>>(xnbuf, sbuf, co);
    k_adot<<<dim3(NN, ND), 128, 0, stream>>>(xnbuf, sbuf, abuf, ctrlU, co);
    k_gramC<<<dim3((co/32)*(co/32), ND), 256, 0, stream>>>(xnbuf, Cbuf, co);
    if (l==0) k_power<256><<<ND, 256, 0, stream>>>(xnbuf, abuf, ctrlU, thB);
    else      k_power<128><<<ND, 256, 0, stream>>>(xnbuf, abuf, ctrlU, thB);
    k_bounds<<<ND, 256, 0, stream>>>(Cbuf, ctrlU, thB, ctrlF, ctrlI, co);

    if (l==0){
      k_eval<256,576,2><<<dim3(MAXB+1, ND), 576, SMEM_D(256), stream>>>(xnbuf, abuf, ctrlF, ctrlI, nuA, tusA);
      k_runs<<<dim3((MAXB+255)/256, ND), 256, 0, stream>>>(nuA, tusA, ctrlI, runP, runB, bnd);
      k_probe<256,576,2><<<dim3(MAXRUN*32, ND), 576, SMEM_D(256), stream>>>(xnbuf, abuf, ctrlI, runP, runB, nuP, tP);
      k_decide<<<ND, 256, 0, stream>>>(ctrlI, runP, runB, nuP, tP, bnd);
    } else {
      k_eval<128,192,3><<<dim3(MAXB+1, ND), 192, SMEM_D(128), stream>>>(xnbuf, abuf, ctrlF, ctrlI, nuA, tusA);
      k_runs<<<dim3((MAXB+255)/256, ND), 256, 0, stream>>>(nuA, tusA, ctrlI, runP, runB, bnd);
      k_probe<128,192,3><<<dim3(MAXRUN*32, ND), 192, SMEM_D(128), stream>>>(xnbuf, abuf, ctrlI, runP, runB, nuP, tP);
      k_decide<<<ND, 256, 0, stream>>>(ctrlI, runP, runB, nuP, tP, bnd);
    }

    k_flags<<<ND, 64, 0, stream>>>(bnd, flagsA, cstart, ctrlI);
    k_cavg<<<dim3(128, ND), 256, 0, stream>>>(gCur, cstart, ctrlI, cavg, co);
    k_clin<<<dim3(128, ND), 256, 0, stream>>>(cavg, linW[l], linb[l], xnbuf, ctrlI, co);

    const float* firPtr;
    if (l==0){
      for (int d=0;d<ND;d++)
        k_gemm<<<dim3(256/64, NN/64, 1), 256, 0, stream>>>(
          dims_in[d], 0, ch1W, 0, ch1b, 0, hbuf + (size_t)d*NN*256, 0, NN, 512, 256);
      firPtr = hbuf;
    } else if (l==1){
      k_gemm<<<dim3(128/64, NN/64, ND), 256, 0, stream>>>(
        oPrev, (long long)NN*256, ch2W, 0, ch2b, 0, hbuf, (long long)NN*128, NN, 256, 128);
      firPtr = hbuf;
    } else {
      firPtr = oPrev;
    }

    k_out<<<dim3(NN, ND), co, 0, stream>>>(firPtr, xnbuf, flagsA, ksv, oCur, co);

    gPrev = gCur; oPrev = oCur;
  }

  k_final<<<NN, 128, 0, stream>>>(oPrev, dimw, (float*)d_out);
}

// Round 7
// 91923.694 us; speedup vs baseline: 2.8043x; 2.8043x over previous
//
#include <hip/hip_runtime.h>
#include <math.h>
#include <stdint.h>

#define NN 2048
#define NE 65536
#define ND 5
#define DMX 256
#define MAXB1 2048
#define SUBD 16
#define NBF (MAXB1*SUBD+1)
#define NFMAX 1536
#define MAXRUN 512
#define COARSE_H 3.52f
#define NUDGE 2e-3f
#define THRG 0.5f

typedef float v2f __attribute__((ext_vector_type(2)));

// ============================ device helpers ============================
__device__ __forceinline__ float wredSum(float v){
#pragma unroll
  for (int o=32;o>0;o>>=1) v += __shfl_down(v,o,64);
  return v;
}
__device__ __forceinline__ float wredMin(float v){
#pragma unroll
  for (int o=32;o>0;o>>=1) v = fminf(v,__shfl_down(v,o,64));
  return v;
}
__device__ __forceinline__ float wredMax(float v){
#pragma unroll
  for (int o=32;o>0;o>>=1) v = fmaxf(v,__shfl_down(v,o,64));
  return v;
}
__device__ __forceinline__ uint32_t encF(float f){
  uint32_t u = __float_as_uint(f);
  return (u & 0x80000000u) ? ~u : (u | 0x80000000u);
}
__device__ __forceinline__ float decF(uint32_t u){
  return (u & 0x80000000u) ? __uint_as_float(u ^ 0x80000000u) : __uint_as_float(~u);
}

template<int BLK>
__device__ float bredSum(float v, float* red){
  v = wredSum(v);
  const int w = threadIdx.x >> 6;
  if ((threadIdx.x & 63) == 0) red[w] = v;
  __syncthreads();
  if (threadIdx.x == 0){
    float s = 0.f;
#pragma unroll
    for (int i=0;i<BLK/64;i++) s += red[i];
    red[0] = s;
  }
  __syncthreads();
  float r = red[0];
  __syncthreads();
  return r;
}

// ============================ nu(t) evaluation ============================
// nu(t) = #{eig(L) < t} = #{a_i < t} + n_-( I - X^T diag(1/(a-t)) X )
// Gram: packed-fp32 (v_pk_fma) 8x8 register tiles.
// Inertia: panel-8 blocked LDL^T — wave0 factors panel wave-synchronously,
// one parallel rank-8 trailing update, 2 barriers/panel.
template<int D, int BLK>
__device__ int evalNu(const float* __restrict__ xn, const float* __restrict__ a,
                      float t0, float dlt,
                      float* M, float* Pt, float* red, float* wrow,
                      float* scal, float* tOut)
{
  const int tid = threadIdx.x;
  constexpr int NTB = D/8;
  constexpr int NT  = NTB*(NTB+1)/2;
  constexpr int XS  = D + 4;   // padded staging stride
  constexpr int PS  = 12;      // Pt stride: 48B -> 16B-aligned, bank-spread

  // ---- phase 1a: nudge t away from poles a_i ----
  float md = 1e30f;
  for (int i=tid;i<NN;i+=BLK) md = fminf(md, fabsf(a[i]-t0));
  md = wredMin(md);
  if ((tid & 63) == 0) red[tid>>6] = md;
  __syncthreads();
  if (tid == 0){
    float m2 = 1e30f;
    for (int i=0;i<BLK/64;i++) m2 = fminf(m2, red[i]);
    scal[1] = (m2 < 1e-3f) ? (t0 + dlt) : t0;
  }
  __syncthreads();
  const float t = scal[1];
  __syncthreads();

  // ---- phase 1b: count a_i < t ----
  float c = 0.f;
  for (int i=tid;i<NN;i+=BLK) c += (a[i] < t) ? 1.f : 0.f;
  float cnt = bredSum<BLK>(c, red);

  // ---- phase 2: G = sum_i w_i x_i x_i^T, packed-fp32 8x8 tiles ----
  int ta = 0, tb = 0;
  if (tid < NT){
    int rem = tid, row = 0;
    while (rem >= NTB - row){ rem -= NTB - row; row++; }
    ta = row; tb = row + rem;
  }
  v2f acc2[32];
#pragma unroll
  for (int i=0;i<32;i++) acc2[i] = (v2f){0.f, 0.f};

  float* xt = M;  // overlay: padded x-tile staging lives where M will go
  for (int i0=0;i0<NN;i0+=16){
    __syncthreads();
    const float4* src = reinterpret_cast<const float4*>(xn + (size_t)i0*D);
    float4* dstv = reinterpret_cast<float4*>(xt);
    for (int l = tid; l < 16*(D/4); l += BLK){
      const int row = l/(D/4), c4 = l%(D/4);
      dstv[row*(XS/4) + c4] = src[l];
    }
    if (tid < 16){
      float den = a[i0+tid] - t;
      if (fabsf(den) < 1e-5f) den = (den < 0.f) ? -1e-5f : 1e-5f;
      wrow[tid] = 1.0f/den;
    }
    __syncthreads();
    if (tid < NT){
#pragma unroll 4
      for (int rs=0;rs<16;rs++){
        const int rr = (rs + tid) & 15;     // lane stagger: spread LDS banks
        const float* xr = xt + rr*XS;
        const float wv = wrow[rr];
        float4 A0 = reinterpret_cast<const float4*>(xr + ta*8)[0];
        float4 A1 = reinterpret_cast<const float4*>(xr + ta*8)[1];
        float4 B0 = reinterpret_cast<const float4*>(xr + tb*8)[0];
        float4 B1 = reinterpret_cast<const float4*>(xr + tb*8)[1];
        float xa[8] = {A0.x*wv,A0.y*wv,A0.z*wv,A0.w*wv,A1.x*wv,A1.y*wv,A1.z*wv,A1.w*wv};
        v2f xb2[4] = {{B0.x,B0.y},{B0.z,B0.w},{B1.x,B1.y},{B1.z,B1.w}};
#pragma unroll
        for (int j=0;j<8;j++){
          const v2f xaj = {xa[j], xa[j]};
#pragma unroll
          for (int m=0;m<4;m++)
            acc2[j*4+m] = __builtin_elementwise_fma(xaj, xb2[m], acc2[j*4+m]);
        }
      }
    }
  }
  __syncthreads();

  // ---- phase 2b: M = I - G, packed upper triangle (row-major) ----
  if (tid < NT){
#pragma unroll
    for (int j=0;j<8;j++){
      int aa = ta*8+j;
      int offa = aa*D - (aa*(aa-1))/2;
#pragma unroll
      for (int mm=0;mm<8;mm++){
        int bb = tb*8+mm;
        if (aa <= bb) M[offa + (bb-aa)] = ((aa==bb)?1.f:0.f) - acc2[j*4+(mm>>1)][mm&1];
      }
    }
  }

  // ---- phase 3: panel-8 blocked LDL^T ----
  int neg = 0;   // meaningful on wave0 (uniform there)
  for (int k0=0; k0<D; k0+=8){
    const int k1 = k0+8;
    __syncthreads();    // prev trailing / phase-2b visible
    if (tid < 64){
      for (int q=k0; q<k1; q++){
        const int offq = q*D - (q*(q-1))/2;
        for (int p=k0; p<q; p++){
          const float cpq = M[p*D - (p*(p-1))/2 + (q-p)];
          const int pc = p - k0;
          for (int j=q+tid; j<D; j+=64)
            M[offq + (j-q)] = fmaf(-cpq, Pt[j*PS + pc], M[offq + (j-q)]);
        }
        __asm__ __volatile__("s_waitcnt lgkmcnt(0)" ::: "memory");
        const float dq = M[offq];
        if (dq < 0.f) neg++;
        float dd = dq;
        if (fabsf(dd) < 1e-8f) dd = (dd<0.f)?-1e-8f:1e-8f;
        const float invd = 1.0f/dd;
        const int qc = q - k0;
        for (int j=q+1+tid; j<D; j+=64)
          Pt[j*PS + qc] = M[offq + (j-q)] * invd;
        __asm__ __volatile__("s_waitcnt lgkmcnt(0)" ::: "memory");
      }
    }
    __syncthreads();    // publish panel rows + Pt
    if (k1 < D){
      constexpr int G = BLK/4;
      const int grp = tid / G, sub = tid % G;
      for (int i0=k1; i0<D; i0+=4){
        const int i = i0 + grp;          // D-k1 multiple of 8 -> valid
        float cq[8];
#pragma unroll
        for (int q=0;q<8;q++){
          const int g = k0+q;
          cq[q] = M[g*D - (g*(g-1))/2 + (i-g)];
        }
        const int offi = i*D - (i*(i-1))/2;
        for (int j=i+sub; j<D; j+=G){
          const float4 p0 = *reinterpret_cast<const float4*>(&Pt[j*PS + 0]);
          const float4 p1 = *reinterpret_cast<const float4*>(&Pt[j*PS + 4]);
          float v = M[offi + (j-i)];
          v = fmaf(-cq[0],p0.x,v); v = fmaf(-cq[1],p0.y,v);
          v = fmaf(-cq[2],p0.z,v); v = fmaf(-cq[3],p0.w,v);
          v = fmaf(-cq[4],p1.x,v); v = fmaf(-cq[5],p1.y,v);
          v = fmaf(-cq[6],p1.z,v); v = fmaf(-cq[7],p1.w,v);
          M[offi + (j-i)] = v;
        }
      }
    }
  }
  if (tid == 0) ((int*)scal)[5] = neg;
  __syncthreads();
  const int negAll = ((int*)scal)[5];
  __syncthreads();

  *tOut = t;
  return negAll + (int)(cnt + 0.5f);
}

#define SMEM_D(D) (((D)*((D)+1)/2 + 12*(D) + 64)*4)

// coarse grid eval
template<int D, int BLK, int WPE>
__global__ __launch_bounds__(BLK,WPE) void k_eval(const float* __restrict__ xnb,
    const float* __restrict__ ab, const float* __restrict__ ctrlF,
    const int* __restrict__ ctrlI, int* __restrict__ nu1, float* __restrict__ tus1)
{
  const int dim = blockIdx.y;
  const int b = blockIdx.x;
  if (b > ctrlI[dim*8+0]) return;
  extern __shared__ float smem[];
  constexpr int TRI = D*(D+1)/2;
  float* M = smem; float* Pt = M+TRI; float* red = Pt + 12*D;
  float* wrow = red+16; float* scal = wrow+16;
  const float lo = ctrlF[dim*8+0], h1 = ctrlF[dim*8+1];
  float tU;
  int v = evalNu<D,BLK>(xnb + (size_t)dim*NN*D, ab + dim*NN, lo + h1*b, NUDGE,
                        M,Pt,red,wrow,scal,&tU);
  if (threadIdx.x == 0){ nu1[dim*(MAXB1+1)+b] = v; tus1[dim*(MAXB1+1)+b] = tU; }
}

// fine eval: 15 interior points per selected coarse bin
template<int D, int BLK, int WPE>
__global__ __launch_bounds__(BLK,WPE) void k_evalF(const float* __restrict__ xnb,
    const float* __restrict__ ab, const float* __restrict__ ctrlF,
    const int* __restrict__ ctrlI, const int* __restrict__ fineBins,
    int* __restrict__ nuF, float* __restrict__ tusF)
{
  const int dim = blockIdx.y;
  const int task = blockIdx.x / 15;
  if (task >= ctrlI[dim*8+3]) return;
  const int s = blockIdx.x % 15 + 1;
  const int bin = fineBins[dim*NFMAX + task];
  extern __shared__ float smem[];
  constexpr int TRI = D*(D+1)/2;
  float* M = smem; float* Pt = M+TRI; float* red = Pt + 12*D;
  float* wrow = red+16; float* scal = wrow+16;
  const float lo = ctrlF[dim*8+0], hf = ctrlF[dim*8+1]*(1.0f/SUBD);
  const int f = bin*SUBD + s;
  float tU;
  int v = evalNu<D,BLK>(xnb + (size_t)dim*NN*D, ab + dim*NN, lo + hf*f, NUDGE,
                        M,Pt,red,wrow,scal,&tU);
  if (threadIdx.x == 0){ nuF[(size_t)dim*NBF+f] = v; tusF[(size_t)dim*NBF+f] = tU; }
}

// one-shot 9-section probes: 8 points per side per ambiguous run, all parallel
template<int D, int BLK, int WPE>
__global__ __launch_bounds__(BLK,WPE) void k_probe(const float* __restrict__ xnb,
    const float* __restrict__ ab, const int* __restrict__ ctrlI,
    const int* __restrict__ runP, const float* __restrict__ runB,
    int* __restrict__ nuP, float* __restrict__ tP)
{
  const int dim = blockIdx.y;
  const int r = blockIdx.x >> 4;
  int nr = ctrlI[dim*8+1]; if (nr > MAXRUN) nr = MAXRUN;
  if (r >= nr) return;
  const int side = (blockIdx.x >> 3) & 1;
  const int i = blockIdx.x & 7;
  extern __shared__ float smem[];
  constexpr int TRI = D*(D+1)/2;
  float* M = smem; float* Pt = M+TRI; float* red = Pt + 12*D;
  float* wrow = red+16; float* scal = wrow+16;
  const float* rb = runB + (size_t)(dim*MAXRUN + r)*4;
  const float lo = rb[side*2+0], hi = rb[side*2+1];
  const float t0 = lo + (hi - lo)*(float)(i+1)*(1.0f/9.0f);
  const float dlt = fminf(NUDGE, (hi-lo)*0.04f);
  float tU;
  int v = evalNu<D,BLK>(xnb + (size_t)dim*NN*D, ab + dim*NN, t0, dlt,
                        M,Pt,red,wrow,scal,&tU);
  if (threadIdx.x == 0){
    const size_t o = (((size_t)dim*MAXRUN + r)*2 + side)*8 + i;
    nuP[o] = v; tP[o] = tU;
  }
}

__global__ void k_decide(const int* __restrict__ ctrlI, const int* __restrict__ runP,
                         const float* __restrict__ runB, const int* __restrict__ nuP,
                         const float* __restrict__ tP, int* __restrict__ bnd){
  const int dim = blockIdx.x;
  int nr = ctrlI[dim*8+1]; if (nr > MAXRUN) nr = MAXRUN;
  for (int r = threadIdx.x; r < nr; r += blockDim.x){
    const int p = runP[dim*MAXRUN + r];
    const float* rb = runB + (size_t)(dim*MAXRUN + r)*4;
    float lam[2];
    for (int side=0; side<2; side++){
      const int rank = p + side;   // nu(t) >= rank  <=>  lam_rank < t
      const size_t o = (((size_t)dim*MAXRUN + r)*2 + side)*8;
      float prev = rb[side*2+0];
      bool found = false; float l = 0.f;
      for (int i=0;i<8;i++){
        const float ti = tP[o+i];
        if (nuP[o+i] >= rank){ l = 0.5f*(prev + ti); found = true; break; }
        prev = ti;
      }
      if (!found) l = 0.5f*(prev + rb[side*2+1]);
      lam[side] = l;
    }
    if (lam[1] - lam[0] > THRG) bnd[dim*NN + p - 1] = 1;
  }
}

// select nonempty coarse bins for subdivision
__global__ void k_sel(const int* __restrict__ nu1, int* ctrlI,
                      int* __restrict__ binSel, int* __restrict__ fineBins){
  const int dim = blockIdx.x;
  if (threadIdx.x) return;
  const int nb1 = ctrlI[dim*8+0];
  const int* nv = nu1 + dim*(MAXB1+1);
  int cnt = 0;
  for (int j=0;j<nb1;j++){
    if (nv[j+1] != nv[j]){
      if (cnt < NFMAX){ binSel[dim*MAXB1+j] = cnt; fineBins[dim*NFMAX+cnt] = j; cnt++; }
      else binSel[dim*MAXB1+j] = -2;
    } else binSel[dim*MAXB1+j] = -1;
  }
  ctrlI[dim*8+3] = cnt;
}

// fill combined fine-resolution arrays (fine eval overwrites its slots after)
__global__ void k_fill(const int* __restrict__ nu1, const float* __restrict__ tus1,
                       const int* __restrict__ binSel, const float* __restrict__ ctrlF,
                       const int* __restrict__ ctrlI,
                       int* __restrict__ nuF, float* __restrict__ tusF){
  const int dim = blockIdx.y;
  const int f = blockIdx.x*256 + threadIdx.x;
  const int nb1 = ctrlI[dim*8+0];
  if (f > nb1*SUBD) return;
  const int j = f / SUBD, s = f % SUBD;
  const float lo = ctrlF[dim*8+0], hf = ctrlF[dim*8+1]*(1.0f/SUBD);
  int v; float tv;
  if (s == 0){ v = nu1[dim*(MAXB1+1)+j]; tv = tus1[dim*(MAXB1+1)+j]; }
  else {
    const int sel = binSel[dim*MAXB1+j];
    tv = lo + hf*f;
    if (sel == -2) v = 0x40000000 + f;       // sentinel: suppress runs here
    else v = nu1[dim*(MAXB1+1)+j];           // empty bin: exact by monotonicity
  }
  nuF[(size_t)dim*NBF+f] = v;
  tusF[(size_t)dim*NBF+f] = tv;
}

// ============================ power iteration for lambda_min(L) ============
template<int D>
__global__ __launch_bounds__(256) void k_power(const float* __restrict__ xnb,
    const float* __restrict__ ab, const uint32_t* __restrict__ ctrlU,
    float* __restrict__ thB)
{
  const int dim = blockIdx.x, tid = threadIdx.x;
  const float* x = xnb + (size_t)dim*NN*D;
  const float* a = ab + dim*NN;
  __shared__ float v[NN];
  __shared__ float z[DMX];
  __shared__ float red[4];
  __shared__ float redR[4];
  __shared__ float sc[2];
  const float amax = decF(ctrlU[dim*8+1]);
  for (int i=tid;i<NN;i+=256){
    uint32_t hsh = (uint32_t)i*2654435761u;
    v[i] = 1.0f + 2e-4f*(float)(hsh>>20);
  }
  __syncthreads();
  float theta = 0.f;
  for (int it=0; it<33; it++){
    if (tid < D){
      float s = 0.f;
      for (int i=0;i<NN;i++) s = fmaf(x[(size_t)i*D+tid], v[i], s);
      z[tid] = s;
    }
    __syncthreads();
    const int grp = tid>>2, sub = tid&3;
    float n2 = 0.f, ray = 0.f;
    const float4* z4 = reinterpret_cast<const float4*>(z);
    for (int p=0;p<NN/64;p++){
      const int i = p*64 + grp;
      const float4* xr = reinterpret_cast<const float4*>(x + (size_t)i*D);
      float dot = 0.f;
      for (int c=sub;c<D/4;c+=4){
        float4 xx = xr[c]; float4 zz = z4[c];
        dot = fmaf(xx.x,zz.x, fmaf(xx.y,zz.y, fmaf(xx.z,zz.z, fmaf(xx.w,zz.w, dot))));
      }
      dot += __shfl_xor(dot,1,64);
      dot += __shfl_xor(dot,2,64);
      const float vi = v[i];
      const float y = (amax - a[i])*vi + dot;
      if (sub==0){ n2 += y*y; ray += vi*y; v[i] = y; }
    }
    __syncthreads();
    n2 = wredSum(n2); ray = wredSum(ray);
    if ((tid&63)==0){ red[tid>>6] = n2; redR[tid>>6] = ray; }
    __syncthreads();
    if (tid==0){
      float s = red[0]+red[1]+red[2]+red[3];
      float r = redR[0]+redR[1]+redR[2]+redR[3];
      sc[0] = rsqrtf(fmaxf(s,1e-30f));
      sc[1] = r;
    }
    __syncthreads();
    theta = sc[1];
    const float inv = sc[0];
    for (int i=tid;i<NN;i+=256) v[i] *= inv;
    __syncthreads();
  }
  if (tid==0) thB[dim] = theta;
}

// ============================ graph / GCN kernels ============================
__global__ void k_init(float* deg, int* cur){
  const int dim = blockIdx.x;
  for (int i=threadIdx.x;i<NN;i+=blockDim.x){ deg[dim*NN+i] = 1.0f; cur[dim*NN+i] = 0; }
}
__global__ void k_count(const int* __restrict__ eidx, const float* __restrict__ ew,
                        float* deg, int* cur){
  const int idx = blockIdx.x*256 + threadIdx.x;
  if (idx >= ND*NE) return;
  const int dim = idx / NE, e = idx % NE;
  const int dst = eidx[(size_t)dim*2*NE + NE + e];
  atomicAdd(&cur[dim*NN + dst], 1);
  atomicAdd(&deg[dim*NN + dst], ew[(size_t)dim*NE + e]);
}
__global__ void k_prefix(int* cur, int* base){
  const int dim = blockIdx.x;
  if (threadIdx.x) return;
  int* b = base + dim*(NN+1);
  int* cc = cur + dim*NN;
  int run = 0; b[0] = 0;
  for (int i=0;i<NN;i++){ int cnt = cc[i]; cc[i] = run; b[i+1] = run + cnt; run += cnt; }
}
__global__ void k_fill_csr(const int* __restrict__ eidx, const float* __restrict__ ew,
                       const float* __restrict__ deg, int* cur, int* psrc, float* coef){
  const int idx = blockIdx.x*256 + threadIdx.x;
  if (idx >= ND*NE) return;
  const int dim = idx / NE, e = idx % NE;
  const int src = eidx[(size_t)dim*2*NE + e];
  const int dst = eidx[(size_t)dim*2*NE + NE + e];
  const int slot = atomicAdd(&cur[dim*NN + dst], 1);
  psrc[(size_t)dim*NE + slot] = src;
  const float ds = deg[dim*NN + src], dd = deg[dim*NN + dst];
  coef[(size_t)dim*NE + slot] = ew[(size_t)dim*NE + e] * (1.0f/sqrtf(ds)) * (1.0f/sqrtf(dd));
}
__global__ void k_selfw(const float* deg, float* sw){
  const int idx = blockIdx.x*256 + threadIdx.x;
  if (idx < ND*NN) sw[idx] = 1.0f/deg[idx];
}

// generic tiled GEMM: C[M,P] = A[M,K] @ W[K,P] (+bias). grid z = dim axis.
__global__ __launch_bounds__(256) void k_gemm(const float* __restrict__ A, long long aStr,
    const float* __restrict__ W, long long wStr,
    const float* __restrict__ bias, long long bStr,
    float* __restrict__ C, long long cStr, int M, int K, int P)
{
  const int dim = blockIdx.z;
  A += (size_t)dim*aStr; W += (size_t)dim*wStr; C += (size_t)dim*cStr;
  if (bias) bias += (size_t)dim*bStr;
  __shared__ float As[64][17];
  __shared__ float Bs[16][68];
  const int tid = threadIdx.x;
  const int tx = tid % 16, ty = tid / 16;
  const int m0 = blockIdx.y*64, p0 = blockIdx.x*64;
  float acc[4][4] = {};
  for (int k0=0;k0<K;k0+=16){
    __syncthreads();
    { int r = tid/4, c4 = (tid%4)*4;
      float4 v = *reinterpret_cast<const float4*>(A + (size_t)(m0+r)*K + k0 + c4);
      As[r][c4]=v.x; As[r][c4+1]=v.y; As[r][c4+2]=v.z; As[r][c4+3]=v.w; }
    { int r = tid/16, c4 = (tid%16)*4;
      float4 v = *reinterpret_cast<const float4*>(W + (size_t)(k0+r)*P + p0 + c4);
      Bs[r][c4]=v.x; Bs[r][c4+1]=v.y; Bs[r][c4+2]=v.z; Bs[r][c4+3]=v.w; }
    __syncthreads();
#pragma unroll
    for (int kk=0;kk<16;kk++){
      float a0=As[ty*4+0][kk], a1=As[ty*4+1][kk], a2=As[ty*4+2][kk], a3=As[ty*4+3][kk];
      float b0=Bs[kk][tx*4+0], b1=Bs[kk][tx*4+1], b2=Bs[kk][tx*4+2], b3=Bs[kk][tx*4+3];
      acc[0][0]=fmaf(a0,b0,acc[0][0]); acc[0][1]=fmaf(a0,b1,acc[0][1]);
      acc[0][2]=fmaf(a0,b2,acc[0][2]); acc[0][3]=fmaf(a0,b3,acc[0][3]);
      acc[1][0]=fmaf(a1,b0,acc[1][0]); acc[1][1]=fmaf(a1,b1,acc[1][1]);
      acc[1][2]=fmaf(a1,b2,acc[1][2]); acc[1][3]=fmaf(a1,b3,acc[1][3]);
      acc[2][0]=fmaf(a2,b0,acc[2][0]); acc[2][1]=fmaf(a2,b1,acc[2][1]);
      acc[2][2]=fmaf(a2,b2,acc[2][2]); acc[2][3]=fmaf(a2,b3,acc[2][3]);
      acc[3][0]=fmaf(a3,b0,acc[3][0]); acc[3][1]=fmaf(a3,b1,acc[3][1]);
      acc[3][2]=fmaf(a3,b2,acc[3][2]); acc[3][3]=fmaf(a3,b3,acc[3][3]);
    }
  }
  for (int i=0;i<4;i++){
    for (int j=0;j<4;j++){
      const int pp = p0 + tx*4 + j;
      float v = acc[i][j];
      if (bias) v += bias[pp];
      C[(size_t)(m0+ty*4+i)*P + pp] = v;
    }
  }
}

__global__ void k_agg(const float* __restrict__ h, float* __restrict__ g,
                      const float* __restrict__ convb, const int* __restrict__ base,
                      const int* __restrict__ psrc, const float* __restrict__ coef,
                      const float* __restrict__ selfw, int co)
{
  const int i = blockIdx.x, dim = blockIdx.y, c = threadIdx.x;
  const float* hD = h + (size_t)dim*NN*co;
  const int s = base[dim*(NN+1)+i], e = base[dim*(NN+1)+i+1];
  const int* ps = psrc + (size_t)dim*NE;
  const float* cf = coef + (size_t)dim*NE;
  float acc = 0.f;
  for (int q=s;q<e;q++) acc += cf[q]*hD[(size_t)ps[q]*co + c];
  g[((size_t)dim*NN+i)*co + c] = acc + hD[(size_t)i*co + c]*selfw[dim*NN+i] + convb[dim*co + c];
}

__global__ void k_rownorm(const float* __restrict__ g, float* __restrict__ xn, int co){
  const int i = blockIdx.x, dim = blockIdx.y;
  const float* gr = g + ((size_t)dim*NN+i)*co;
  float* xr = xn + ((size_t)dim*NN+i)*co;
  float p = 0.f;
  for (int c=threadIdx.x;c<co;c+=256){ float v = gr[c]; p += v*v; }
  __shared__ float red[4];
  p = wredSum(p);
  if ((threadIdx.x&63)==0) red[threadIdx.x>>6] = p;
  __syncthreads();
  if (threadIdx.x==0) red[0] = red[0]+red[1]+red[2]+red[3];
  __syncthreads();
  const float inv = 1.0f/(sqrtf(red[0]) + 1e-8f);
  for (int c=threadIdx.x;c<co;c+=256) xr[c] = gr[c]*inv;
}

__global__ void k_colsum(const float* __restrict__ xn, float* __restrict__ sb, int co){
  const int c = blockIdx.x*64 + threadIdx.x;
  const int dim = blockIdx.y;
  const float* x = xn + (size_t)dim*NN*co;
  float s = 0.f;
  for (int i=0;i<NN;i++) s += x[(size_t)i*co + c];
  sb[dim*DMX + c] = s;
}

__global__ void k_adot(const float* __restrict__ xn, const float* __restrict__ sb,
                       float* __restrict__ ab, uint32_t* ctrlU, int co){
  const int i = blockIdx.x, dim = blockIdx.y;
  const float* x = xn + ((size_t)dim*NN + i)*co;
  const float* s = sb + dim*DMX;
  float p = 0.f;
  for (int c=threadIdx.x;c<co;c+=128) p += x[c]*s[c];
  p = wredSum(p);
  __shared__ float red[2];
  if ((threadIdx.x&63)==0) red[threadIdx.x>>6] = p;
  __syncthreads();
  if (threadIdx.x==0){
    const float v = red[0] + red[1];
    ab[dim*NN+i] = v;
    const uint32_t e = encF(v);
    atomicMin(&ctrlU[dim*8+0], e);
    atomicMax(&ctrlU[dim*8+1], e);
  }
}

__global__ __launch_bounds__(256) void k_gramC(const float* __restrict__ xn,
                                               float* __restrict__ Cb, int co){
  const int dim = blockIdx.y;
  const int nbx = co/32;
  const int bx = blockIdx.x % nbx, by = blockIdx.x / nbx;
  const float* x = xn + (size_t)dim*NN*co;
  float* C = Cb + (size_t)dim*co*co;
  __shared__ float Xa[64][33];
  __shared__ float Xb[64][33];
  const int tid = threadIdx.x;
  const int ty = tid/16, tx = tid%16;
  float a00=0,a01=0,a10=0,a11=0;
  for (int i0=0;i0<NN;i0+=64){
    __syncthreads();
    for (int l=tid;l<512;l+=256){
      const int r = l/8, c4 = (l%8)*4;
      float4 va = *reinterpret_cast<const float4*>(x + (size_t)(i0+r)*co + by*32 + c4);
      Xa[r][c4]=va.x; Xa[r][c4+1]=va.y; Xa[r][c4+2]=va.z; Xa[r][c4+3]=va.w;
      float4 vb = *reinterpret_cast<const float4*>(x + (size_t)(i0+r)*co + bx*32 + c4);
      Xb[r][c4]=vb.x; Xb[r][c4+1]=vb.y; Xb[r][c4+2]=vb.z; Xb[r][c4+3]=vb.w;
    }
    __syncthreads();
#pragma unroll 8
    for (int r=0;r<64;r++){
      const float u0=Xa[r][ty*2], u1=Xa[r][ty*2+1], w0=Xb[r][tx*2], w1=Xb[r][tx*2+1];
      a00=fmaf(u0,w0,a00); a01=fmaf(u0,w1,a01); a10=fmaf(u1,w0,a10); a11=fmaf(u1,w1,a11);
    }
  }
  const int ca = by*32 + ty*2, cb = bx*32 + tx*2;
  C[(size_t)(ca+0)*co + cb+0]=a00; C[(size_t)(ca+0)*co + cb+1]=a01;
  C[(size_t)(ca+1)*co + cb+0]=a10; C[(size_t)(ca+1)*co + cb+1]=a11;
}

__global__ void k_layerinit(int* bnd, uint32_t* ctrlU, int* ctrlI){
  const int dim = blockIdx.x;
  for (int i=threadIdx.x;i<NN;i+=blockDim.x) bnd[dim*NN+i] = 0;
  if (threadIdx.x==0){
    ctrlU[dim*8+0] = 0xFFFFFFFFu;
    ctrlU[dim*8+1] = 0u;
    ctrlI[dim*8+1] = 0;
    ctrlI[dim*8+3] = 0;
  }
}

// lo = max(amin - gersh(C), amax - theta - pad); coarse bins of width <= COARSE_H
__global__ __launch_bounds__(256) void k_bounds(const float* __restrict__ Cb,
                         const uint32_t* ctrlU, const float* __restrict__ thB,
                         float* ctrlF, int* ctrlI, int co){
  const int dim = blockIdx.x, tid = threadIdx.x;
  const float* C = Cb + (size_t)dim*co*co;
  __shared__ float red[4];
  float rs = 0.f;
  if (tid < co){
    const float* row = C + (size_t)tid*co;
    for (int b=0;b<co;b++) rs += fabsf(row[b]);
  }
  float mx = wredMax(rs);
  if ((tid&63)==0) red[tid>>6] = mx;
  __syncthreads();
  if (tid==0){
    const float gersh = fmaxf(fmaxf(red[0],red[1]), fmaxf(red[2],red[3]));
    const float amin = decF(ctrlU[dim*8+0]);
    const float amax = decF(ctrlU[dim*8+1]);
    const float th = thB[dim];
    const float loG = amin - gersh;
    const float loP = amax - th - (0.02f*fabsf(th) + 0.5f);
    const float lo = fmaxf(loG, loP) - 0.05f;
    const float hi = amax + 0.1f;
    int nb = (int)ceilf((hi - lo)/COARSE_H);
    if (nb > MAXB1) nb = MAXB1;
    if (nb < 8) nb = 8;
    ctrlF[dim*8+0] = lo;
    ctrlF[dim*8+1] = (hi - lo)/nb;   // h1
    ctrlI[dim*8+0] = nb;             // nb1
  }
}

__global__ void k_runs(const int* __restrict__ nuF, const float* __restrict__ tusF,
                       int* ctrlI, int* runP, float* runB, int* bnd){
  const int dim = blockIdx.x;
  if (threadIdx.x) return;
  const int nbt = ctrlI[dim*8+0]*SUBD;
  const int* nv = nuF + (size_t)dim*NBF;
  const float* tu = tusF + (size_t)dim*NBF;
  int nr = 0, b = 0;
  while (b < nbt){
    if (nv[b+1] == nv[b]){
      const int b1 = b; int j2 = b;
      while (j2+1 < nbt && nv[j2+2] == nv[j2+1]) j2++;
      const int p = nv[b1];
      if (p >= 1 && p <= NN-1 && b1 >= 1 && j2 <= nbt-2){
        const float gmin = tu[j2+1] - tu[b1];
        const float gmax = tu[j2+2] - tu[b1-1];
        if (gmin > THRG) bnd[dim*NN + p-1] = 1;
        else if (gmax > THRG && nr < MAXRUN){
          runP[dim*MAXRUN+nr] = p;
          float* rb = runB + (size_t)(dim*MAXRUN+nr)*4;
          rb[0]=tu[b1-1]; rb[1]=tu[b1]; rb[2]=tu[j2+1]; rb[3]=tu[j2+2];
          nr++;
        }
      }
      b = j2+1;
    } else b++;
  }
  ctrlI[dim*8+1] = nr;
}

__global__ void k_flags(const int* __restrict__ bnd, int* flags, int* cstart, int* ctrlI){
  const int dim = blockIdx.x;
  if (threadIdx.x) return;
  const int* b = bnd + dim*NN;
  int* f = flags + dim*NN;
  int* cs = cstart + dim*(NN+1);
  int cur = 0; f[0] = 0; cs[0] = 0;
  for (int i=1;i<NN;i++){
    cur += b[i-1];
    f[i] = cur;
    if (b[i-1]) cs[cur] = i;
  }
  ctrlI[dim*8+2] = cur+1;
  cs[cur+1] = NN;
}

__global__ void k_cavg(const float* __restrict__ g, const int* __restrict__ cstart,
                       const int* __restrict__ ctrlI, float* __restrict__ cavg, int co){
  const int dim = blockIdx.y;
  const int nc = ctrlI[dim*8+2];
  const float* gD = g + (size_t)dim*NN*co;
  const int cc = threadIdx.x;
  for (int c = blockIdx.x; c < nc; c += gridDim.x){
    const int s = cstart[dim*(NN+1)+c], e = cstart[dim*(NN+1)+c+1];
    const float inv = 1.0f/(float)(e - s);
    if (cc < co){
      float acc = 0.f;
      for (int i=s;i<e;i++) acc += gD[(size_t)i*co + cc];
      cavg[((size_t)dim*NN + c)*co + cc] = acc*inv;
    }
  }
}

__global__ void k_clin(const float* __restrict__ cavg, const float* __restrict__ linW,
                       const float* __restrict__ linb, float* __restrict__ clin,
                       const int* __restrict__ ctrlI, int co){
  const int dim = blockIdx.y;
  const int nc = ctrlI[dim*8+2];
  __shared__ float row[DMX];
  const int tid = threadIdx.x;
  for (int c = blockIdx.x; c < nc; c += gridDim.x){
    const float* av = cavg + ((size_t)dim*NN + c)*co;
    __syncthreads();
    if (tid < co) row[tid] = av[tid];
    __syncthreads();
    if (tid < co){
      float s = linb[tid];
      for (int k=0;k<co;k++) s = fmaf(row[k], linW[(size_t)k*co + tid], s);
      clin[((size_t)dim*NN + c)*co + tid] = s;
    }
  }
}

__global__ void k_out(const float* __restrict__ fir, const float* __restrict__ clin,
                      const int* __restrict__ flags, const float* __restrict__ ksv,
                      float* __restrict__ out, int co){
  const int i = blockIdx.x, dim = blockIdx.y, c = threadIdx.x;
  const float kv = ksv[0];
  const int cls = flags[dim*NN+i];
  const float fv = fir[((size_t)dim*NN+i)*co + c];
  const float lv = clin[((size_t)dim*NN+cls)*co + c];
  const float o = 2.f*fv + kv*lv;
  out[((size_t)dim*NN+i)*co + c] = (o > 0.f) ? o : 0.f;
}

__global__ void k_final(const float* __restrict__ outL, const float* __restrict__ dimw,
                        float* __restrict__ o){
  const int i = blockIdx.x, c = threadIdx.x;
  float w[ND]; float ws = 0.f;
#pragma unroll
  for (int d=0;d<ND;d++){ w[d] = dimw[d]; ws += w[d]; }
  float v = 0.f;
#pragma unroll
  for (int d=0;d<ND;d++) v += (w[d]/ws) * outL[((size_t)d*NN + i)*128 + c];
  o[(size_t)i*128 + c] = v;
}

// ============================ host ============================
extern "C" void kernel_launch(void* const* d_in, const int* in_sizes, int n_in,
                              void* d_out, int out_size, void* d_ws, size_t ws_size,
                              hipStream_t stream)
{
  const float* dims_in[ND];
  for (int d=0;d<ND;d++) dims_in[d] = (const float*)d_in[d];
  const int*   eidx = (const int*)d_in[5];
  const float* ew   = (const float*)d_in[6];
  const float* convW[6]; const float* convb[6];
  for (int l=0;l<6;l++){ convW[l] = (const float*)d_in[8+2*l]; convb[l] = (const float*)d_in[9+2*l]; }
  const float* linW[6]; const float* linb[6];
  for (int l=0;l<6;l++){ linW[l] = (const float*)d_in[20+2*l]; linb[l] = (const float*)d_in[21+2*l]; }
  const float* ch1W = (const float*)d_in[32]; const float* ch1b = (const float*)d_in[33];
  const float* ch2W = (const float*)d_in[34]; const float* ch2b = (const float*)d_in[35];
  const float* dimw = (const float*)d_in[36]; const float* ksv = (const float*)d_in[37];

  // ---- carve workspace ----
  char* p = (char*)d_ws;
  auto take = [&](size_t bytes)->char*{
    char* r = p; p += (bytes + 255) & ~(size_t)255; return r;
  };
  int*   csr_base = (int*)  take((size_t)ND*(NN+1)*4);
  int*   csr_cur  = (int*)  take((size_t)ND*NN*4);
  int*   csr_psrc = (int*)  take((size_t)ND*NE*4);
  float* csr_coef = (float*)take((size_t)ND*NE*4);
  float* deg      = (float*)take((size_t)ND*NN*4);
  float* selfw    = (float*)take((size_t)ND*NN*4);
  float* gA   = (float*)take((size_t)ND*NN*DMX*4);
  float* gB   = (float*)take((size_t)ND*NN*DMX*4);
  float* outA = (float*)take((size_t)ND*NN*DMX*4);
  float* outB = (float*)take((size_t)ND*NN*DMX*4);
  float* hbuf = (float*)take((size_t)ND*NN*DMX*4);
  float* xnbuf= (float*)take((size_t)ND*NN*DMX*4);
  float* cavg = (float*)take((size_t)ND*NN*DMX*4);
  float* abuf = (float*)take((size_t)ND*NN*4);
  float* sbuf = (float*)take((size_t)ND*DMX*4);
  float* Cbuf = (float*)take((size_t)ND*DMX*DMX*4);
  int*   nu1  = (int*)  take((size_t)ND*(MAXB1+1)*4);
  float* tus1 = (float*)take((size_t)ND*(MAXB1+1)*4);
  int*   nuF  = (int*)  take((size_t)ND*NBF*4);
  float* tusF = (float*)take((size_t)ND*NBF*4);
  int*   binSel=(int*)  take((size_t)ND*MAXB1*4);
  int*   fineBins=(int*)take((size_t)ND*NFMAX*4);
  int*   runP = (int*)  take((size_t)ND*MAXRUN*4);
  float* runB = (float*)take((size_t)ND*MAXRUN*4*4);
  int*   nuP  = (int*)  take((size_t)ND*MAXRUN*2*8*4);
  float* tP   = (float*)take((size_t)ND*MAXRUN*2*8*4);
  int*   bnd  = (int*)  take((size_t)ND*NN*4);
  int*   flagsA=(int*)  take((size_t)ND*NN*4);
  int*   cstart=(int*)  take((size_t)ND*(NN+1)*4);
  float* ctrlF= (float*)take((size_t)ND*8*4);
  uint32_t* ctrlU = (uint32_t*)take((size_t)ND*8*4);
  int*   ctrlI= (int*)  take((size_t)ND*8*4);
  float* thB  = (float*)take((size_t)ND*4);
  (void)ws_size; (void)in_sizes; (void)n_in; (void)out_size;

  // ---- allow >64KB dynamic LDS for the D=256 eval kernels ----
  {
    void (*pe)(const float*,const float*,const float*,const int*,int*,float*) = k_eval<256,576,2>;
    hipFuncSetAttribute((const void*)pe, hipFuncAttributeMaxDynamicSharedMemorySize, SMEM_D(256));
    void (*pf)(const float*,const float*,const float*,const int*,const int*,int*,float*) = k_evalF<256,576,2>;
    hipFuncSetAttribute((const void*)pf, hipFuncAttributeMaxDynamicSharedMemorySize, SMEM_D(256));
    void (*pp)(const float*,const float*,const int*,const int*,const float*,int*,float*) = k_probe<256,576,2>;
    hipFuncSetAttribute((const void*)pp, hipFuncAttributeMaxDynamicSharedMemorySize, SMEM_D(256));
  }

  // ---- CSR setup (edges fixed across layers) ----
  k_init<<<ND, 256, 0, stream>>>(deg, csr_cur);
  k_count<<<(ND*NE+255)/256, 256, 0, stream>>>(eidx, ew, deg, csr_cur);
  k_prefix<<<ND, 64, 0, stream>>>(csr_cur, csr_base);
  k_fill_csr<<<(ND*NE+255)/256, 256, 0, stream>>>(eidx, ew, deg, csr_cur, csr_psrc, csr_coef);
  k_selfw<<<(ND*NN+255)/256, 256, 0, stream>>>(deg, selfw);

  float* gbufs[2] = {gA, gB};
  float* obufs[2] = {outA, outB};
  const float* gPrev = nullptr;
  const float* oPrev = nullptr;

  for (int l=0;l<6;l++){
    const int co = (l==0) ? 256 : 128;
    const int ci = (l==0) ? 512 : ((l==1) ? 256 : 128);
    float* gCur = gbufs[l&1];
    float* oCur = obufs[l&1];

    if (l==0){
      for (int d=0;d<ND;d++)
        k_gemm<<<dim3(256/64, NN/64, 1), 256, 0, stream>>>(
          dims_in[d], 0, convW[0] + (size_t)d*512*256, 0, nullptr, 0,
          hbuf + (size_t)d*NN*256, 0, NN, 512, 256);
    } else {
      k_gemm<<<dim3(co/64, NN/64, ND), 256, 0, stream>>>(
        gPrev, (long long)NN*ci, convW[l], (long long)ci*co, nullptr, 0,
        hbuf, (long long)NN*co, NN, ci, co);
    }

    k_layerinit<<<ND, 256, 0, stream>>>(bnd, ctrlU, ctrlI);
    k_agg<<<dim3(NN, ND), co, 0, stream>>>(hbuf, gCur, convb[l], csr_base, csr_psrc,
                                           csr_coef, selfw, co);
    k_rownorm<<<dim3(NN, ND), 256, 0, stream>>>(gCur, xnbuf, co);
    k_colsum<<<dim3(co/64, ND), 64, 0, stream>>>(xnbuf, sbuf, co);
    k_adot<<<dim3(NN, ND), 128, 0, stream>>>(xnbuf, sbuf, abuf, ctrlU, co);
    k_gramC<<<dim3((co/32)*(co/32), ND), 256, 0, stream>>>(xnbuf, Cbuf, co);
    if (l==0) k_power<256><<<ND, 256, 0, stream>>>(xnbuf, abuf, ctrlU, thB);
    else      k_power<128><<<ND, 256, 0, stream>>>(xnbuf, abuf, ctrlU, thB);
    k_bounds<<<ND, 256, 0, stream>>>(Cbuf, ctrlU, thB, ctrlF, ctrlI, co);

    if (l==0){
      k_eval<256,576,2><<<dim3(MAXB1+1, ND), 576, SMEM_D(256), stream>>>(xnbuf, abuf, ctrlF, ctrlI, nu1, tus1);
      k_sel<<<ND, 64, 0, stream>>>(nu1, ctrlI, binSel, fineBins);
      k_fill<<<dim3((NBF+255)/256, ND), 256, 0, stream>>>(nu1, tus1, binSel, ctrlF, ctrlI, nuF, tusF);
      k_evalF<256,576,2><<<dim3(NFMAX*15, ND), 576, SMEM_D(256), stream>>>(xnbuf, abuf, ctrlF, ctrlI, fineBins, nuF, tusF);
      k_runs<<<ND, 64, 0, stream>>>(nuF, tusF, ctrlI, runP, runB, bnd);
      k_probe<256,576,2><<<dim3(MAXRUN*16, ND), 576, SMEM_D(256), stream>>>(xnbuf, abuf, ctrlI, runP, runB, nuP, tP);
      k_decide<<<ND, 256, 0, stream>>>(ctrlI, runP, runB, nuP, tP, bnd);
    } else {
      k_eval<128,192,3><<<dim3(MAXB1+1, ND), 192, SMEM_D(128), stream>>>(xnbuf, abuf, ctrlF, ctrlI, nu1, tus1);
      k_sel<<<ND, 64, 0, stream>>>(nu1, ctrlI, binSel, fineBins);
      k_fill<<<dim3((NBF+255)/256, ND), 256, 0, stream>>>(nu1, tus1, binSel, ctrlF, ctrlI, nuF, tusF);
      k_evalF<128,192,3><<<dim3(NFMAX*15, ND), 192, SMEM_D(128), stream>>>(xnbuf, abuf, ctrlF, ctrlI, fineBins, nuF, tusF);
      k_runs<<<ND, 64, 0, stream>>>(nuF, tusF, ctrlI, runP, runB, bnd);
      k_probe<128,192,3><<<dim3(MAXRUN*16, ND), 192, SMEM_D(128), stream>>>(xnbuf, abuf, ctrlI, runP, runB, nuP, tP);
      k_decide<<<ND, 256, 0, stream>>>(ctrlI, runP, runB, nuP, tP, bnd);
    }

    k_flags<<<ND, 64, 0, stream>>>(bnd, flagsA, cstart, ctrlI);
    k_cavg<<<dim3(128, ND), 256, 0, stream>>>(gCur, cstart, ctrlI, cavg, co);
    k_clin<<<dim3(128, ND), 256, 0, stream>>>(cavg, linW[l], linb[l], xnbuf, ctrlI, co);

    const float* firPtr;
    if (l==0){
      for (int d=0;d<ND;d++)
        k_gemm<<<dim3(256/64, NN/64, 1), 256, 0, stream>>>(
          dims_in[d], 0, ch1W, 0, ch1b, 0, hbuf + (size_t)d*NN*256, 0, NN, 512, 256);
      firPtr = hbuf;
    } else if (l==1){
      k_gemm<<<dim3(128/64, NN/64, ND), 256, 0, stream>>>(
        oPrev, (long long)NN*256, ch2W, 0, ch2b, 0, hbuf, (long long)NN*128, NN, 256, 128);
      firPtr = hbuf;
    } else {
      firPtr = oPrev;
    }

    k_out<<<dim3(NN, ND), co, 0, stream>>>(firPtr, xnbuf, flagsA, ksv, oCur, co);

    gPrev = gCur; oPrev = oCur;
  }

  k_final<<<NN, 128, 0, stream>>>(oPrev, dimw, (float*)d_out);
}

// Round 8
// 90004.095 us; speedup vs baseline: 2.8641x; 1.0213x over previous
//
#include <hip/hip_runtime.h>
#include <math.h>
#include <stdint.h>

#define NN 2048
#define NE 65536
#define ND 5
#define DMX 256
#define MAXB1 2048
#define SUBD 8
#define NBF (MAXB1*SUBD+1)
#define NFMAX 1536
#define MAXRUN 1536
#define NPB 4
#define COARSE_H 1.76f
#define NUDGE 2e-3f
#define THRG 0.5f

typedef float v2f __attribute__((ext_vector_type(2)));

// ============================ device helpers ============================
__device__ __forceinline__ float wredSum(float v){
#pragma unroll
  for (int o=32;o>0;o>>=1) v += __shfl_down(v,o,64);
  return v;
}
__device__ __forceinline__ float wredMin(float v){
#pragma unroll
  for (int o=32;o>0;o>>=1) v = fminf(v,__shfl_down(v,o,64));
  return v;
}
__device__ __forceinline__ float wredMax(float v){
#pragma unroll
  for (int o=32;o>0;o>>=1) v = fmaxf(v,__shfl_down(v,o,64));
  return v;
}
__device__ __forceinline__ uint32_t encF(float f){
  uint32_t u = __float_as_uint(f);
  return (u & 0x80000000u) ? ~u : (u | 0x80000000u);
}
__device__ __forceinline__ float decF(uint32_t u){
  return (u & 0x80000000u) ? __uint_as_float(u ^ 0x80000000u) : __uint_as_float(~u);
}

template<int BLK>
__device__ float bredSum(float v, float* red){
  v = wredSum(v);
  const int w = threadIdx.x >> 6;
  if ((threadIdx.x & 63) == 0) red[w] = v;
  __syncthreads();
  if (threadIdx.x == 0){
    float s = 0.f;
#pragma unroll
    for (int i=0;i<BLK/64;i++) s += red[i];
    red[0] = s;
  }
  __syncthreads();
  float r = red[0];
  __syncthreads();
  return r;
}

// ============================ nu(t) evaluation ============================
// nu(t) = #{eig(L) < t} = #{a_i < t} + n_-( I - X^T diag(1/(a-t)) X )
// Gram: packed-fp32 (v_pk_fma) 8x8 register tiles.
// Inertia: panel-8 blocked LDL^T — wave0 factors panel wave-synchronously,
// one parallel rank-8 trailing update, 2 barriers/panel.
template<int D, int BLK>
__device__ int evalNu(const float* __restrict__ xn, const float* __restrict__ a,
                      float t0, float dlt,
                      float* M, float* Pt, float* red, float* wrow,
                      float* scal, float* tOut)
{
  const int tid = threadIdx.x;
  constexpr int NTB = D/8;
  constexpr int NT  = NTB*(NTB+1)/2;
  constexpr int XS  = D + 4;   // padded staging stride
  constexpr int PS  = 12;      // Pt stride: 48B -> 16B-aligned, bank-spread

  // ---- phase 1a: nudge t away from poles a_i ----
  float md = 1e30f;
  for (int i=tid;i<NN;i+=BLK) md = fminf(md, fabsf(a[i]-t0));
  md = wredMin(md);
  if ((tid & 63) == 0) red[tid>>6] = md;
  __syncthreads();
  if (tid == 0){
    float m2 = 1e30f;
    for (int i=0;i<BLK/64;i++) m2 = fminf(m2, red[i]);
    scal[1] = (m2 < 1e-3f) ? (t0 + dlt) : t0;
  }
  __syncthreads();
  const float t = scal[1];
  __syncthreads();

  // ---- phase 1b: count a_i < t ----
  float c = 0.f;
  for (int i=tid;i<NN;i+=BLK) c += (a[i] < t) ? 1.f : 0.f;
  float cnt = bredSum<BLK>(c, red);

  // ---- phase 2: G = sum_i w_i x_i x_i^T, packed-fp32 8x8 tiles ----
  int ta = 0, tb = 0;
  if (tid < NT){
    int rem = tid, row = 0;
    while (rem >= NTB - row){ rem -= NTB - row; row++; }
    ta = row; tb = row + rem;
  }
  v2f acc2[32];
#pragma unroll
  for (int i=0;i<32;i++) acc2[i] = (v2f){0.f, 0.f};

  float* xt = M;  // overlay: padded x-tile staging lives where M will go
  for (int i0=0;i0<NN;i0+=16){
    __syncthreads();
    const float4* src = reinterpret_cast<const float4*>(xn + (size_t)i0*D);
    float4* dstv = reinterpret_cast<float4*>(xt);
    for (int l = tid; l < 16*(D/4); l += BLK){
      const int row = l/(D/4), c4 = l%(D/4);
      dstv[row*(XS/4) + c4] = src[l];
    }
    if (tid < 16){
      float den = a[i0+tid] - t;
      if (fabsf(den) < 1e-5f) den = (den < 0.f) ? -1e-5f : 1e-5f;
      wrow[tid] = 1.0f/den;
    }
    __syncthreads();
    if (tid < NT){
#pragma unroll 4
      for (int rs=0;rs<16;rs++){
        const int rr = (rs + tid) & 15;     // lane stagger: spread LDS banks
        const float* xr = xt + rr*XS;
        const float wv = wrow[rr];
        float4 A0 = reinterpret_cast<const float4*>(xr + ta*8)[0];
        float4 A1 = reinterpret_cast<const float4*>(xr + ta*8)[1];
        float4 B0 = reinterpret_cast<const float4*>(xr + tb*8)[0];
        float4 B1 = reinterpret_cast<const float4*>(xr + tb*8)[1];
        float xa[8] = {A0.x*wv,A0.y*wv,A0.z*wv,A0.w*wv,A1.x*wv,A1.y*wv,A1.z*wv,A1.w*wv};
        v2f xb2[4] = {{B0.x,B0.y},{B0.z,B0.w},{B1.x,B1.y},{B1.z,B1.w}};
#pragma unroll
        for (int j=0;j<8;j++){
          const v2f xaj = {xa[j], xa[j]};
#pragma unroll
          for (int m=0;m<4;m++)
            acc2[j*4+m] = __builtin_elementwise_fma(xaj, xb2[m], acc2[j*4+m]);
        }
      }
    }
  }
  __syncthreads();

  // ---- phase 2b: M = I - G, packed upper triangle (row-major) ----
  if (tid < NT){
#pragma unroll
    for (int j=0;j<8;j++){
      int aa = ta*8+j;
      int offa = aa*D - (aa*(aa-1))/2;
#pragma unroll
      for (int mm=0;mm<8;mm++){
        int bb = tb*8+mm;
        if (aa <= bb) M[offa + (bb-aa)] = ((aa==bb)?1.f:0.f) - acc2[j*4+(mm>>1)][mm&1];
      }
    }
  }

  // ---- phase 3: panel-8 blocked LDL^T ----
  int neg = 0;   // meaningful on wave0 (uniform there)
  for (int k0=0; k0<D; k0+=8){
    const int k1 = k0+8;
    __syncthreads();    // prev trailing / phase-2b visible
    if (tid < 64){
      for (int q=k0; q<k1; q++){
        const int offq = q*D - (q*(q-1))/2;
        for (int p=k0; p<q; p++){
          const float cpq = M[p*D - (p*(p-1))/2 + (q-p)];
          const int pc = p - k0;
          for (int j=q+tid; j<D; j+=64)
            M[offq + (j-q)] = fmaf(-cpq, Pt[j*PS + pc], M[offq + (j-q)]);
        }
        __asm__ __volatile__("s_waitcnt lgkmcnt(0)" ::: "memory");
        const float dq = M[offq];
        if (dq < 0.f) neg++;
        float dd = dq;
        if (fabsf(dd) < 1e-8f) dd = (dd<0.f)?-1e-8f:1e-8f;
        const float invd = 1.0f/dd;
        const int qc = q - k0;
        for (int j=q+1+tid; j<D; j+=64)
          Pt[j*PS + qc] = M[offq + (j-q)] * invd;
        __asm__ __volatile__("s_waitcnt lgkmcnt(0)" ::: "memory");
      }
    }
    __syncthreads();    // publish panel rows + Pt
    if (k1 < D){
      constexpr int G = BLK/4;
      const int grp = tid / G, sub = tid % G;
      for (int i0=k1; i0<D; i0+=4){
        const int i = i0 + grp;          // D-k1 multiple of 8 -> valid
        float cq[8];
#pragma unroll
        for (int q=0;q<8;q++){
          const int g = k0+q;
          cq[q] = M[g*D - (g*(g-1))/2 + (i-g)];
        }
        const int offi = i*D - (i*(i-1))/2;
        for (int j=i+sub; j<D; j+=G){
          const float4 p0 = *reinterpret_cast<const float4*>(&Pt[j*PS + 0]);
          const float4 p1 = *reinterpret_cast<const float4*>(&Pt[j*PS + 4]);
          float v = M[offi + (j-i)];
          v = fmaf(-cq[0],p0.x,v); v = fmaf(-cq[1],p0.y,v);
          v = fmaf(-cq[2],p0.z,v); v = fmaf(-cq[3],p0.w,v);
          v = fmaf(-cq[4],p1.x,v); v = fmaf(-cq[5],p1.y,v);
          v = fmaf(-cq[6],p1.z,v); v = fmaf(-cq[7],p1.w,v);
          M[offi + (j-i)] = v;
        }
      }
    }
  }
  if (tid == 0) ((int*)scal)[5] = neg;
  __syncthreads();
  const int negAll = ((int*)scal)[5];
  __syncthreads();

  *tOut = t;
  return negAll + (int)(cnt + 0.5f);
}

#define SMEM_D(D) (((D)*((D)+1)/2 + 12*(D) + 64)*4)

// coarse grid eval
template<int D, int BLK, int WPE>
__global__ __launch_bounds__(BLK,WPE) void k_eval(const float* __restrict__ xnb,
    const float* __restrict__ ab, const float* __restrict__ ctrlF,
    const int* __restrict__ ctrlI, int* __restrict__ nu1, float* __restrict__ tus1)
{
  const int dim = blockIdx.y;
  const int b = blockIdx.x;
  if (b > ctrlI[dim*8+0]) return;
  extern __shared__ float smem[];
  constexpr int TRI = D*(D+1)/2;
  float* M = smem; float* Pt = M+TRI; float* red = Pt + 12*D;
  float* wrow = red+16; float* scal = wrow+16;
  const float lo = ctrlF[dim*8+0], h1 = ctrlF[dim*8+1];
  float tU;
  int v = evalNu<D,BLK>(xnb + (size_t)dim*NN*D, ab + dim*NN, lo + h1*b, NUDGE,
                        M,Pt,red,wrow,scal,&tU);
  if (threadIdx.x == 0){ nu1[dim*(MAXB1+1)+b] = v; tus1[dim*(MAXB1+1)+b] = tU; }
}

// fine eval: SUBD-1 interior points per selected coarse bin
template<int D, int BLK, int WPE>
__global__ __launch_bounds__(BLK,WPE) void k_evalF(const float* __restrict__ xnb,
    const float* __restrict__ ab, const float* __restrict__ ctrlF,
    const int* __restrict__ ctrlI, const int* __restrict__ fineBins,
    int* __restrict__ nuF, float* __restrict__ tusF)
{
  const int dim = blockIdx.y;
  const int task = blockIdx.x / (SUBD-1);
  int cnt = ctrlI[dim*8+3]; if (cnt > NFMAX) cnt = NFMAX;
  if (task >= cnt) return;
  const int s = blockIdx.x % (SUBD-1) + 1;
  const int bin = fineBins[dim*NFMAX + task];
  extern __shared__ float smem[];
  constexpr int TRI = D*(D+1)/2;
  float* M = smem; float* Pt = M+TRI; float* red = Pt + 12*D;
  float* wrow = red+16; float* scal = wrow+16;
  const float lo = ctrlF[dim*8+0], hf = ctrlF[dim*8+1]*(1.0f/SUBD);
  const int f = bin*SUBD + s;
  float tU;
  int v = evalNu<D,BLK>(xnb + (size_t)dim*NN*D, ab + dim*NN, lo + hf*f, NUDGE,
                        M,Pt,red,wrow,scal,&tU);
  if (threadIdx.x == 0){ nuF[(size_t)dim*NBF+f] = v; tusF[(size_t)dim*NBF+f] = tU; }
}

// one-shot probes: NPB points per side per ambiguous run, all parallel
template<int D, int BLK, int WPE>
__global__ __launch_bounds__(BLK,WPE) void k_probe(const float* __restrict__ xnb,
    const float* __restrict__ ab, const int* __restrict__ ctrlI,
    const int* __restrict__ runP, const float* __restrict__ runB,
    int* __restrict__ nuP, float* __restrict__ tP)
{
  const int dim = blockIdx.y;
  const int r = blockIdx.x >> 3;
  int nr = ctrlI[dim*8+1]; if (nr > MAXRUN) nr = MAXRUN;
  if (r >= nr) return;
  const int side = (blockIdx.x >> 2) & 1;
  const int i = blockIdx.x & 3;
  extern __shared__ float smem[];
  constexpr int TRI = D*(D+1)/2;
  float* M = smem; float* Pt = M+TRI; float* red = Pt + 12*D;
  float* wrow = red+16; float* scal = wrow+16;
  const float* rb = runB + (size_t)(dim*MAXRUN + r)*4;
  const float lo = rb[side*2+0], hi = rb[side*2+1];
  const float t0 = lo + (hi - lo)*(float)(i+1)*(1.0f/(NPB+1));
  const float dlt = fminf(NUDGE, (hi-lo)*0.08f);
  float tU;
  int v = evalNu<D,BLK>(xnb + (size_t)dim*NN*D, ab + dim*NN, t0, dlt,
                        M,Pt,red,wrow,scal,&tU);
  if (threadIdx.x == 0){
    const size_t o = (((size_t)dim*MAXRUN + r)*2 + side)*NPB + i;
    nuP[o] = v; tP[o] = tU;
  }
}

__global__ void k_decide(const int* __restrict__ ctrlI, const int* __restrict__ runP,
                         const float* __restrict__ runB, const int* __restrict__ nuP,
                         const float* __restrict__ tP, int* __restrict__ bnd){
  const int dim = blockIdx.x;
  int nr = ctrlI[dim*8+1]; if (nr > MAXRUN) nr = MAXRUN;
  for (int r = threadIdx.x; r < nr; r += blockDim.x){
    const int p = runP[dim*MAXRUN + r];
    const float* rb = runB + (size_t)(dim*MAXRUN + r)*4;
    float lam[2];
    for (int side=0; side<2; side++){
      const int rank = p + side;   // nu(t) >= rank  <=>  lam_rank < t
      const size_t o = (((size_t)dim*MAXRUN + r)*2 + side)*NPB;
      float prev = rb[side*2+0];
      bool found = false; float l = 0.f;
      for (int i=0;i<NPB;i++){
        const float ti = tP[o+i];
        if (nuP[o+i] >= rank){ l = 0.5f*(prev + ti); found = true; break; }
        prev = ti;
      }
      if (!found) l = 0.5f*(prev + rb[side*2+1]);
      lam[side] = l;
    }
    if (lam[1] - lam[0] > THRG) bnd[dim*NN + p - 1] = 1;
  }
}

// select nonempty coarse bins for subdivision (parallel, atomic append)
__global__ void k_sel(const int* __restrict__ nu1, int* ctrlI,
                      int* __restrict__ binSel, int* __restrict__ fineBins){
  const int dim = blockIdx.y;
  const int j = blockIdx.x*256 + threadIdx.x;
  const int nb1 = ctrlI[dim*8+0];
  if (j >= nb1) return;
  const int* nv = nu1 + dim*(MAXB1+1);
  if (nv[j+1] != nv[j]){
    const int slot = atomicAdd(&ctrlI[dim*8+3], 1);
    if (slot < NFMAX){ binSel[dim*MAXB1+j] = slot; fineBins[dim*NFMAX+slot] = j; }
    else binSel[dim*MAXB1+j] = -2;
  } else binSel[dim*MAXB1+j] = -1;
}

// fill combined fine-resolution arrays (fine eval overwrites its slots after)
__global__ void k_fill(const int* __restrict__ nu1, const float* __restrict__ tus1,
                       const int* __restrict__ binSel, const float* __restrict__ ctrlF,
                       const int* __restrict__ ctrlI,
                       int* __restrict__ nuF, float* __restrict__ tusF){
  const int dim = blockIdx.y;
  const int f = blockIdx.x*256 + threadIdx.x;
  const int nb1 = ctrlI[dim*8+0];
  if (f > nb1*SUBD) return;
  const int j = f / SUBD, s = f % SUBD;
  const float lo = ctrlF[dim*8+0], hf = ctrlF[dim*8+1]*(1.0f/SUBD);
  int v; float tv;
  if (s == 0){ v = nu1[dim*(MAXB1+1)+j]; tv = tus1[dim*(MAXB1+1)+j]; }
  else {
    const int sel = binSel[dim*MAXB1+j];
    tv = lo + hf*f;
    if (sel == -2) v = 0x40000000 + f;       // sentinel: suppress runs here
    else v = nu1[dim*(MAXB1+1)+j];           // empty bin: exact by monotonicity
  }
  nuF[(size_t)dim*NBF+f] = v;
  tusF[(size_t)dim*NBF+f] = tv;
}

// parallel run detection on the merged fine array
__global__ void k_runs(const int* __restrict__ nuF, const float* __restrict__ tusF,
                       int* ctrlI, int* __restrict__ runP, float* __restrict__ runB,
                       int* __restrict__ bnd){
  const int dim = blockIdx.y;
  const int b1 = blockIdx.x*256 + threadIdx.x;
  const int nbt = ctrlI[dim*8+0]*SUBD;
  if (b1 >= nbt) return;
  const int* nv = nuF + (size_t)dim*NBF;
  const float* tu = tusF + (size_t)dim*NBF;
  if (nv[b1+1] != nv[b1]) return;              // not an empty bin
  if (b1 > 0 && nv[b1-1] == nv[b1]) return;    // not the run start
  int j2 = b1;
  while (j2+1 < nbt && nv[j2+2] == nv[j2+1]) j2++;
  const int p = nv[b1];
  if (p < 1 || p > NN-1 || b1 < 1 || j2 > nbt-2) return;
  const float gmin = tu[j2+1] - tu[b1];
  const float gmax = tu[j2+2] - tu[b1-1];
  if (gmin > THRG){ bnd[dim*NN + p-1] = 1; return; }
  if (gmax > THRG){
    const int slot = atomicAdd(&ctrlI[dim*8+1], 1);
    if (slot < MAXRUN){
      runP[dim*MAXRUN + slot] = p;
      float* rb = runB + (size_t)(dim*MAXRUN + slot)*4;
      rb[0]=tu[b1-1]; rb[1]=tu[b1]; rb[2]=tu[j2+1]; rb[3]=tu[j2+2];
    }
  }
}

// ============================ power iteration for lambda_min(L) ============
template<int D>
__global__ __launch_bounds__(256) void k_power(const float* __restrict__ xnb,
    const float* __restrict__ ab, const uint32_t* __restrict__ ctrlU,
    float* __restrict__ thB)
{
  const int dim = blockIdx.x, tid = threadIdx.x;
  const float* x = xnb + (size_t)dim*NN*D;
  const float* a = ab + dim*NN;
  __shared__ float v[NN];
  __shared__ float z[DMX];
  __shared__ float red[4];
  __shared__ float redR[4];
  __shared__ float sc[2];
  const float amax = decF(ctrlU[dim*8+1]);
  for (int i=tid;i<NN;i+=256){
    uint32_t hsh = (uint32_t)i*2654435761u;
    v[i] = 1.0f + 2e-4f*(float)(hsh>>20);
  }
  __syncthreads();
  float theta = 0.f;
  for (int it=0; it<33; it++){
    if (tid < D){
      float s = 0.f;
      for (int i=0;i<NN;i++) s = fmaf(x[(size_t)i*D+tid], v[i], s);
      z[tid] = s;
    }
    __syncthreads();
    const int grp = tid>>2, sub = tid&3;
    float n2 = 0.f, ray = 0.f;
    const float4* z4 = reinterpret_cast<const float4*>(z);
    for (int p=0;p<NN/64;p++){
      const int i = p*64 + grp;
      const float4* xr = reinterpret_cast<const float4*>(x + (size_t)i*D);
      float dot = 0.f;
      for (int c=sub;c<D/4;c+=4){
        float4 xx = xr[c]; float4 zz = z4[c];
        dot = fmaf(xx.x,zz.x, fmaf(xx.y,zz.y, fmaf(xx.z,zz.z, fmaf(xx.w,zz.w, dot))));
      }
      dot += __shfl_xor(dot,1,64);
      dot += __shfl_xor(dot,2,64);
      const float vi = v[i];
      const float y = (amax - a[i])*vi + dot;
      if (sub==0){ n2 += y*y; ray += vi*y; v[i] = y; }
    }
    __syncthreads();
    n2 = wredSum(n2); ray = wredSum(ray);
    if ((tid&63)==0){ red[tid>>6] = n2; redR[tid>>6] = ray; }
    __syncthreads();
    if (tid==0){
      float s = red[0]+red[1]+red[2]+red[3];
      float r = redR[0]+redR[1]+redR[2]+redR[3];
      sc[0] = rsqrtf(fmaxf(s,1e-30f));
      sc[1] = r;
    }
    __syncthreads();
    theta = sc[1];
    const float inv = sc[0];
    for (int i=tid;i<NN;i+=256) v[i] *= inv;
    __syncthreads();
  }
  if (tid==0) thB[dim] = theta;
}

// ============================ graph / GCN kernels ============================
__global__ void k_init(float* deg, int* cur){
  const int dim = blockIdx.x;
  for (int i=threadIdx.x;i<NN;i+=blockDim.x){ deg[dim*NN+i] = 1.0f; cur[dim*NN+i] = 0; }
}
__global__ void k_count(const int* __restrict__ eidx, const float* __restrict__ ew,
                        float* deg, int* cur){
  const int idx = blockIdx.x*256 + threadIdx.x;
  if (idx >= ND*NE) return;
  const int dim = idx / NE, e = idx % NE;
  const int dst = eidx[(size_t)dim*2*NE + NE + e];
  atomicAdd(&cur[dim*NN + dst], 1);
  atomicAdd(&deg[dim*NN + dst], ew[(size_t)dim*NE + e]);
}
__global__ void k_prefix(int* cur, int* base){
  const int dim = blockIdx.x;
  if (threadIdx.x) return;
  int* b = base + dim*(NN+1);
  int* cc = cur + dim*NN;
  int run = 0; b[0] = 0;
  for (int i=0;i<NN;i++){ int cnt = cc[i]; cc[i] = run; b[i+1] = run + cnt; run += cnt; }
}
__global__ void k_fill_csr(const int* __restrict__ eidx, const float* __restrict__ ew,
                       const float* __restrict__ deg, int* cur, int* psrc, float* coef){
  const int idx = blockIdx.x*256 + threadIdx.x;
  if (idx >= ND*NE) return;
  const int dim = idx / NE, e = idx % NE;
  const int src = eidx[(size_t)dim*2*NE + e];
  const int dst = eidx[(size_t)dim*2*NE + NE + e];
  const int slot = atomicAdd(&cur[dim*NN + dst], 1);
  psrc[(size_t)dim*NE + slot] = src;
  const float ds = deg[dim*NN + src], dd = deg[dim*NN + dst];
  coef[(size_t)dim*NE + slot] = ew[(size_t)dim*NE + e] * (1.0f/sqrtf(ds)) * (1.0f/sqrtf(dd));
}
__global__ void k_selfw(const float* deg, float* sw){
  const int idx = blockIdx.x*256 + threadIdx.x;
  if (idx < ND*NN) sw[idx] = 1.0f/deg[idx];
}

// generic tiled GEMM: C[M,P] = A[M,K] @ W[K,P] (+bias). grid z = dim axis.
__global__ __launch_bounds__(256) void k_gemm(const float* __restrict__ A, long long aStr,
    const float* __restrict__ W, long long wStr,
    const float* __restrict__ bias, long long bStr,
    float* __restrict__ C, long long cStr, int M, int K, int P)
{
  const int dim = blockIdx.z;
  A += (size_t)dim*aStr; W += (size_t)dim*wStr; C += (size_t)dim*cStr;
  if (bias) bias += (size_t)dim*bStr;
  __shared__ float As[64][17];
  __shared__ float Bs[16][68];
  const int tid = threadIdx.x;
  const int tx = tid % 16, ty = tid / 16;
  const int m0 = blockIdx.y*64, p0 = blockIdx.x*64;
  float acc[4][4] = {};
  for (int k0=0;k0<K;k0+=16){
    __syncthreads();
    { int r = tid/4, c4 = (tid%4)*4;
      float4 v = *reinterpret_cast<const float4*>(A + (size_t)(m0+r)*K + k0 + c4);
      As[r][c4]=v.x; As[r][c4+1]=v.y; As[r][c4+2]=v.z; As[r][c4+3]=v.w; }
    { int r = tid/16, c4 = (tid%16)*4;
      float4 v = *reinterpret_cast<const float4*>(W + (size_t)(k0+r)*P + p0 + c4);
      Bs[r][c4]=v.x; Bs[r][c4+1]=v.y; Bs[r][c4+2]=v.z; Bs[r][c4+3]=v.w; }
    __syncthreads();
#pragma unroll
    for (int kk=0;kk<16;kk++){
      float a0=As[ty*4+0][kk], a1=As[ty*4+1][kk], a2=As[ty*4+2][kk], a3=As[ty*4+3][kk];
      float b0=Bs[kk][tx*4+0], b1=Bs[kk][tx*4+1], b2=Bs[kk][tx*4+2], b3=Bs[kk][tx*4+3];
      acc[0][0]=fmaf(a0,b0,acc[0][0]); acc[0][1]=fmaf(a0,b1,acc[0][1]);
      acc[0][2]=fmaf(a0,b2,acc[0][2]); acc[0][3]=fmaf(a0,b3,acc[0][3]);
      acc[1][0]=fmaf(a1,b0,acc[1][0]); acc[1][1]=fmaf(a1,b1,acc[1][1]);
      acc[1][2]=fmaf(a1,b2,acc[1][2]); acc[1][3]=fmaf(a1,b3,acc[1][3]);
      acc[2][0]=fmaf(a2,b0,acc[2][0]); acc[2][1]=fmaf(a2,b1,acc[2][1]);
      acc[2][2]=fmaf(a2,b2,acc[2][2]); acc[2][3]=fmaf(a2,b3,acc[2][3]);
      acc[3][0]=fmaf(a3,b0,acc[3][0]); acc[3][1]=fmaf(a3,b1,acc[3][1]);
      acc[3][2]=fmaf(a3,b2,acc[3][2]); acc[3][3]=fmaf(a3,b3,acc[3][3]);
    }
  }
  for (int i=0;i<4;i++){
    for (int j=0;j<4;j++){
      const int pp = p0 + tx*4 + j;
      float v = acc[i][j];
      if (bias) v += bias[pp];
      C[(size_t)(m0+ty*4+i)*P + pp] = v;
    }
  }
}

__global__ void k_agg(const float* __restrict__ h, float* __restrict__ g,
                      const float* __restrict__ convb, const int* __restrict__ base,
                      const int* __restrict__ psrc, const float* __restrict__ coef,
                      const float* __restrict__ selfw, int co)
{
  const int i = blockIdx.x, dim = blockIdx.y, c = threadIdx.x;
  const float* hD = h + (size_t)dim*NN*co;
  const int s = base[dim*(NN+1)+i], e = base[dim*(NN+1)+i+1];
  const int* ps = psrc + (size_t)dim*NE;
  const float* cf = coef + (size_t)dim*NE;
  float acc = 0.f;
  for (int q=s;q<e;q++) acc += cf[q]*hD[(size_t)ps[q]*co + c];
  g[((size_t)dim*NN+i)*co + c] = acc + hD[(size_t)i*co + c]*selfw[dim*NN+i] + convb[dim*co + c];
}

__global__ void k_rownorm(const float* __restrict__ g, float* __restrict__ xn, int co){
  const int i = blockIdx.x, dim = blockIdx.y;
  const float* gr = g + ((size_t)dim*NN+i)*co;
  float* xr = xn + ((size_t)dim*NN+i)*co;
  float p = 0.f;
  for (int c=threadIdx.x;c<co;c+=256){ float v = gr[c]; p += v*v; }
  __shared__ float red[4];
  p = wredSum(p);
  if ((threadIdx.x&63)==0) red[threadIdx.x>>6] = p;
  __syncthreads();
  if (threadIdx.x==0) red[0] = red[0]+red[1]+red[2]+red[3];
  __syncthreads();
  const float inv = 1.0f/(sqrtf(red[0]) + 1e-8f);
  for (int c=threadIdx.x;c<co;c+=256) xr[c] = gr[c]*inv;
}

__global__ void k_colsum(const float* __restrict__ xn, float* __restrict__ sb, int co){
  const int c = blockIdx.x*64 + threadIdx.x;
  const int dim = blockIdx.y;
  const float* x = xn + (size_t)dim*NN*co;
  float s = 0.f;
  for (int i=0;i<NN;i++) s += x[(size_t)i*co + c];
  sb[dim*DMX + c] = s;
}

__global__ void k_adot(const float* __restrict__ xn, const float* __restrict__ sb,
                       float* __restrict__ ab, uint32_t* ctrlU, int co){
  const int i = blockIdx.x, dim = blockIdx.y;
  const float* x = xn + ((size_t)dim*NN + i)*co;
  const float* s = sb + dim*DMX;
  float p = 0.f;
  for (int c=threadIdx.x;c<co;c+=128) p += x[c]*s[c];
  p = wredSum(p);
  __shared__ float red[2];
  if ((threadIdx.x&63)==0) red[threadIdx.x>>6] = p;
  __syncthreads();
  if (threadIdx.x==0){
    const float v = red[0] + red[1];
    ab[dim*NN+i] = v;
    const uint32_t e = encF(v);
    atomicMin(&ctrlU[dim*8+0], e);
    atomicMax(&ctrlU[dim*8+1], e);
  }
}

__global__ __launch_bounds__(256) void k_gramC(const float* __restrict__ xn,
                                               float* __restrict__ Cb, int co){
  const int dim = blockIdx.y;
  const int nbx = co/32;
  const int bx = blockIdx.x % nbx, by = blockIdx.x / nbx;
  const float* x = xn + (size_t)dim*NN*co;
  float* C = Cb + (size_t)dim*co*co;
  __shared__ float Xa[64][33];
  __shared__ float Xb[64][33];
  const int tid = threadIdx.x;
  const int ty = tid/16, tx = tid%16;
  float a00=0,a01=0,a10=0,a11=0;
  for (int i0=0;i0<NN;i0+=64){
    __syncthreads();
    for (int l=tid;l<512;l+=256){
      const int r = l/8, c4 = (l%8)*4;
      float4 va = *reinterpret_cast<const float4*>(x + (size_t)(i0+r)*co + by*32 + c4);
      Xa[r][c4]=va.x; Xa[r][c4+1]=va.y; Xa[r][c4+2]=va.z; Xa[r][c4+3]=va.w;
      float4 vb = *reinterpret_cast<const float4*>(x + (size_t)(i0+r)*co + bx*32 + c4);
      Xb[r][c4]=vb.x; Xb[r][c4+1]=vb.y; Xb[r][c4+2]=vb.z; Xb[r][c4+3]=vb.w;
    }
    __syncthreads();
#pragma unroll 8
    for (int r=0;r<64;r++){
      const float u0=Xa[r][ty*2], u1=Xa[r][ty*2+1], w0=Xb[r][tx*2], w1=Xb[r][tx*2+1];
      a00=fmaf(u0,w0,a00); a01=fmaf(u0,w1,a01); a10=fmaf(u1,w0,a10); a11=fmaf(u1,w1,a11);
    }
  }
  const int ca = by*32 + ty*2, cb = bx*32 + tx*2;
  C[(size_t)(ca+0)*co + cb+0]=a00; C[(size_t)(ca+0)*co + cb+1]=a01;
  C[(size_t)(ca+1)*co + cb+0]=a10; C[(size_t)(ca+1)*co + cb+1]=a11;
}

__global__ void k_layerinit(int* bnd, uint32_t* ctrlU, int* ctrlI){
  const int dim = blockIdx.x;
  for (int i=threadIdx.x;i<NN;i+=blockDim.x) bnd[dim*NN+i] = 0;
  if (threadIdx.x==0){
    ctrlU[dim*8+0] = 0xFFFFFFFFu;
    ctrlU[dim*8+1] = 0u;
    ctrlI[dim*8+1] = 0;
    ctrlI[dim*8+3] = 0;
  }
}

// lo = max(amin - gersh(C), amax - theta - pad); coarse bins of width <= COARSE_H
__global__ __launch_bounds__(256) void k_bounds(const float* __restrict__ Cb,
                         const uint32_t* ctrlU, const float* __restrict__ thB,
                         float* ctrlF, int* ctrlI, int co){
  const int dim = blockIdx.x, tid = threadIdx.x;
  const float* C = Cb + (size_t)dim*co*co;
  __shared__ float red[4];
  float rs = 0.f;
  if (tid < co){
    const float* row = C + (size_t)tid*co;
    for (int b=0;b<co;b++) rs += fabsf(row[b]);
  }
  float mx = wredMax(rs);
  if ((tid&63)==0) red[tid>>6] = mx;
  __syncthreads();
  if (tid==0){
    const float gersh = fmaxf(fmaxf(red[0],red[1]), fmaxf(red[2],red[3]));
    const float amin = decF(ctrlU[dim*8+0]);
    const float amax = decF(ctrlU[dim*8+1]);
    const float th = thB[dim];
    const float loG = amin - gersh;
    const float loP = amax - th - (0.02f*fabsf(th) + 0.5f);
    const float lo = fmaxf(loG, loP) - 0.05f;
    const float hi = amax + 0.1f;
    int nb = (int)ceilf((hi - lo)/COARSE_H);
    if (nb > MAXB1) nb = MAXB1;
    if (nb < 8) nb = 8;
    ctrlF[dim*8+0] = lo;
    ctrlF[dim*8+1] = (hi - lo)/nb;   // h1
    ctrlI[dim*8+0] = nb;             // nb1
  }
}

__global__ void k_flags(const int* __restrict__ bnd, int* flags, int* cstart, int* ctrlI){
  const int dim = blockIdx.x;
  if (threadIdx.x) return;
  const int* b = bnd + dim*NN;
  int* f = flags + dim*NN;
  int* cs = cstart + dim*(NN+1);
  int cur = 0; f[0] = 0; cs[0] = 0;
  for (int i=1;i<NN;i++){
    cur += b[i-1];
    f[i] = cur;
    if (b[i-1]) cs[cur] = i;
  }
  ctrlI[dim*8+2] = cur+1;
  cs[cur+1] = NN;
}

__global__ void k_cavg(const float* __restrict__ g, const int* __restrict__ cstart,
                       const int* __restrict__ ctrlI, float* __restrict__ cavg, int co){
  const int dim = blockIdx.y;
  const int nc = ctrlI[dim*8+2];
  const float* gD = g + (size_t)dim*NN*co;
  const int cc = threadIdx.x;
  for (int c = blockIdx.x; c < nc; c += gridDim.x){
    const int s = cstart[dim*(NN+1)+c], e = cstart[dim*(NN+1)+c+1];
    const float inv = 1.0f/(float)(e - s);
    if (cc < co){
      float acc = 0.f;
      for (int i=s;i<e;i++) acc += gD[(size_t)i*co + cc];
      cavg[((size_t)dim*NN + c)*co + cc] = acc*inv;
    }
  }
}

__global__ void k_clin(const float* __restrict__ cavg, const float* __restrict__ linW,
                       const float* __restrict__ linb, float* __restrict__ clin,
                       const int* __restrict__ ctrlI, int co){
  const int dim = blockIdx.y;
  const int nc = ctrlI[dim*8+2];
  __shared__ float row[DMX];
  const int tid = threadIdx.x;
  for (int c = blockIdx.x; c < nc; c += gridDim.x){
    const float* av = cavg + ((size_t)dim*NN + c)*co;
    __syncthreads();
    if (tid < co) row[tid] = av[tid];
    __syncthreads();
    if (tid < co){
      float s = linb[tid];
      for (int k=0;k<co;k++) s = fmaf(row[k], linW[(size_t)k*co + tid], s);
      clin[((size_t)dim*NN + c)*co + tid] = s;
    }
  }
}

__global__ void k_out(const float* __restrict__ fir, const float* __restrict__ clin,
                      const int* __restrict__ flags, const float* __restrict__ ksv,
                      float* __restrict__ out, int co){
  const int i = blockIdx.x, dim = blockIdx.y, c = threadIdx.x;
  const float kv = ksv[0];
  const int cls = flags[dim*NN+i];
  const float fv = fir[((size_t)dim*NN+i)*co + c];
  const float lv = clin[((size_t)dim*NN+cls)*co + c];
  const float o = 2.f*fv + kv*lv;
  out[((size_t)dim*NN+i)*co + c] = (o > 0.f) ? o : 0.f;
}

__global__ void k_final(const float* __restrict__ outL, const float* __restrict__ dimw,
                        float* __restrict__ o){
  const int i = blockIdx.x, c = threadIdx.x;
  float w[ND]; float ws = 0.f;
#pragma unroll
  for (int d=0;d<ND;d++){ w[d] = dimw[d]; ws += w[d]; }
  float v = 0.f;
#pragma unroll
  for (int d=0;d<ND;d++) v += (w[d]/ws) * outL[((size_t)d*NN + i)*128 + c];
  o[(size_t)i*128 + c] = v;
}

// ============================ host ============================
extern "C" void kernel_launch(void* const* d_in, const int* in_sizes, int n_in,
                              void* d_out, int out_size, void* d_ws, size_t ws_size,
                              hipStream_t stream)
{
  const float* dims_in[ND];
  for (int d=0;d<ND;d++) dims_in[d] = (const float*)d_in[d];
  const int*   eidx = (const int*)d_in[5];
  const float* ew   = (const float*)d_in[6];
  const float* convW[6]; const float* convb[6];
  for (int l=0;l<6;l++){ convW[l] = (const float*)d_in[8+2*l]; convb[l] = (const float*)d_in[9+2*l]; }
  const float* linW[6]; const float* linb[6];
  for (int l=0;l<6;l++){ linW[l] = (const float*)d_in[20+2*l]; linb[l] = (const float*)d_in[21+2*l]; }
  const float* ch1W = (const float*)d_in[32]; const float* ch1b = (const float*)d_in[33];
  const float* ch2W = (const float*)d_in[34]; const float* ch2b = (const float*)d_in[35];
  const float* dimw = (const float*)d_in[36]; const float* ksv = (const float*)d_in[37];

  // ---- carve workspace ----
  char* p = (char*)d_ws;
  auto take = [&](size_t bytes)->char*{
    char* r = p; p += (bytes + 255) & ~(size_t)255; return r;
  };
  int*   csr_base = (int*)  take((size_t)ND*(NN+1)*4);
  int*   csr_cur  = (int*)  take((size_t)ND*NN*4);
  int*   csr_psrc = (int*)  take((size_t)ND*NE*4);
  float* csr_coef = (float*)take((size_t)ND*NE*4);
  float* deg      = (float*)take((size_t)ND*NN*4);
  float* selfw    = (float*)take((size_t)ND*NN*4);
  float* gA   = (float*)take((size_t)ND*NN*DMX*4);
  float* gB   = (float*)take((size_t)ND*NN*DMX*4);
  float* outA = (float*)take((size_t)ND*NN*DMX*4);
  float* outB = (float*)take((size_t)ND*NN*DMX*4);
  float* hbuf = (float*)take((size_t)ND*NN*DMX*4);
  float* xnbuf= (float*)take((size_t)ND*NN*DMX*4);
  float* cavg = (float*)take((size_t)ND*NN*DMX*4);
  float* abuf = (float*)take((size_t)ND*NN*4);
  float* sbuf = (float*)take((size_t)ND*DMX*4);
  float* Cbuf = (float*)take((size_t)ND*DMX*DMX*4);
  int*   nu1  = (int*)  take((size_t)ND*(MAXB1+1)*4);
  float* tus1 = (float*)take((size_t)ND*(MAXB1+1)*4);
  int*   nuF  = (int*)  take((size_t)ND*NBF*4);
  float* tusF = (float*)take((size_t)ND*NBF*4);
  int*   binSel=(int*)  take((size_t)ND*MAXB1*4);
  int*   fineBins=(int*)take((size_t)ND*NFMAX*4);
  int*   runP = (int*)  take((size_t)ND*MAXRUN*4);
  float* runB = (float*)take((size_t)ND*MAXRUN*4*4);
  int*   nuP  = (int*)  take((size_t)ND*MAXRUN*2*NPB*4);
  float* tP   = (float*)take((size_t)ND*MAXRUN*2*NPB*4);
  int*   bnd  = (int*)  take((size_t)ND*NN*4);
  int*   flagsA=(int*)  take((size_t)ND*NN*4);
  int*   cstart=(int*)  take((size_t)ND*(NN+1)*4);
  float* ctrlF= (float*)take((size_t)ND*8*4);
  uint32_t* ctrlU = (uint32_t*)take((size_t)ND*8*4);
  int*   ctrlI= (int*)  take((size_t)ND*8*4);
  float* thB  = (float*)take((size_t)ND*4);
  (void)ws_size; (void)in_sizes; (void)n_in; (void)out_size;

  // ---- allow >64KB dynamic LDS for the D=256 eval kernels ----
  {
    void (*pe)(const float*,const float*,const float*,const int*,int*,float*) = k_eval<256,576,2>;
    hipFuncSetAttribute((const void*)pe, hipFuncAttributeMaxDynamicSharedMemorySize, SMEM_D(256));
    void (*pf)(const float*,const float*,const float*,const int*,const int*,int*,float*) = k_evalF<256,576,2>;
    hipFuncSetAttribute((const void*)pf, hipFuncAttributeMaxDynamicSharedMemorySize, SMEM_D(256));
    void (*pp)(const float*,const float*,const int*,const int*,const float*,int*,float*) = k_probe<256,576,2>;
    hipFuncSetAttribute((const void*)pp, hipFuncAttributeMaxDynamicSharedMemorySize, SMEM_D(256));
  }

  // ---- CSR setup (edges fixed across layers) ----
  k_init<<<ND, 256, 0, stream>>>(deg, csr_cur);
  k_count<<<(ND*NE+255)/256, 256, 0, stream>>>(eidx, ew, deg, csr_cur);
  k_prefix<<<ND, 64, 0, stream>>>(csr_cur, csr_base);
  k_fill_csr<<<(ND*NE+255)/256, 256, 0, stream>>>(eidx, ew, deg, csr_cur, csr_psrc, csr_coef);
  k_selfw<<<(ND*NN+255)/256, 256, 0, stream>>>(deg, selfw);

  float* gbufs[2] = {gA, gB};
  float* obufs[2] = {outA, outB};
  const float* gPrev = nullptr;
  const float* oPrev = nullptr;

  for (int l=0;l<6;l++){
    const int co = (l==0) ? 256 : 128;
    const int ci = (l==0) ? 512 : ((l==1) ? 256 : 128);
    float* gCur = gbufs[l&1];
    float* oCur = obufs[l&1];

    if (l==0){
      for (int d=0;d<ND;d++)
        k_gemm<<<dim3(256/64, NN/64, 1), 256, 0, stream>>>(
          dims_in[d], 0, convW[0] + (size_t)d*512*256, 0, nullptr, 0,
          hbuf + (size_t)d*NN*256, 0, NN, 512, 256);
    } else {
      k_gemm<<<dim3(co/64, NN/64, ND), 256, 0, stream>>>(
        gPrev, (long long)NN*ci, convW[l], (long long)ci*co, nullptr, 0,
        hbuf, (long long)NN*co, NN, ci, co);
    }

    k_layerinit<<<ND, 256, 0, stream>>>(bnd, ctrlU, ctrlI);
    k_agg<<<dim3(NN, ND), co, 0, stream>>>(hbuf, gCur, convb[l], csr_base, csr_psrc,
                                           csr_coef, selfw, co);
    k_rownorm<<<dim3(NN, ND), 256, 0, stream>>>(gCur, xnbuf, co);
    k_colsum<<<dim3(co/64, ND), 64, 0, stream>>>(xnbuf, sbuf, co);
    k_adot<<<dim3(NN, ND), 128, 0, stream>>>(xnbuf, sbuf, abuf, ctrlU, co);
    k_gramC<<<dim3((co/32)*(co/32), ND), 256, 0, stream>>>(xnbuf, Cbuf, co);
    if (l==0) k_power<256><<<ND, 256, 0, stream>>>(xnbuf, abuf, ctrlU, thB);
    else      k_power<128><<<ND, 256, 0, stream>>>(xnbuf, abuf, ctrlU, thB);
    k_bounds<<<ND, 256, 0, stream>>>(Cbuf, ctrlU, thB, ctrlF, ctrlI, co);

    if (l==0){
      k_eval<256,576,2><<<dim3(MAXB1+1, ND), 576, SMEM_D(256), stream>>>(xnbuf, abuf, ctrlF, ctrlI, nu1, tus1);
      k_sel<<<dim3((MAXB1+255)/256, ND), 256, 0, stream>>>(nu1, ctrlI, binSel, fineBins);
      k_fill<<<dim3((NBF+255)/256, ND), 256, 0, stream>>>(nu1, tus1, binSel, ctrlF, ctrlI, nuF, tusF);
      k_evalF<256,576,2><<<dim3(NFMAX*(SUBD-1), ND), 576, SMEM_D(256), stream>>>(xnbuf, abuf, ctrlF, ctrlI, fineBins, nuF, tusF);
      k_runs<<<dim3((NBF+255)/256, ND), 256, 0, stream>>>(nuF, tusF, ctrlI, runP, runB, bnd);
      k_probe<256,576,2><<<dim3(MAXRUN*2*NPB, ND), 576, SMEM_D(256), stream>>>(xnbuf, abuf, ctrlI, runP, runB, nuP, tP);
      k_decide<<<ND, 256, 0, stream>>>(ctrlI, runP, runB, nuP, tP, bnd);
    } else {
      k_eval<128,192,3><<<dim3(MAXB1+1, ND), 192, SMEM_D(128), stream>>>(xnbuf, abuf, ctrlF, ctrlI, nu1, tus1);
      k_sel<<<dim3((MAXB1+255)/256, ND), 256, 0, stream>>>(nu1, ctrlI, binSel, fineBins);
      k_fill<<<dim3((NBF+255)/256, ND), 256, 0, stream>>>(nu1, tus1, binSel, ctrlF, ctrlI, nuF, tusF);
      k_evalF<128,192,3><<<dim3(NFMAX*(SUBD-1), ND), 192, SMEM_D(128), stream>>>(xnbuf, abuf, ctrlF, ctrlI, fineBins, nuF, tusF);
      k_runs<<<dim3((NBF+255)/256, ND), 256, 0, stream>>>(nuF, tusF, ctrlI, runP, runB, bnd);
      k_probe<128,192,3><<<dim3(MAXRUN*2*NPB, ND), 192, SMEM_D(128), stream>>>(xnbuf, abuf, ctrlI, runP, runB, nuP, tP);
      k_decide<<<ND, 256, 0, stream>>>(ctrlI, runP, runB, nuP, tP, bnd);
    }

    k_flags<<<ND, 64, 0, stream>>>(bnd, flagsA, cstart, ctrlI);
    k_cavg<<<dim3(128, ND), 256, 0, stream>>>(gCur, cstart, ctrlI, cavg, co);
    k_clin<<<dim3(128, ND), 256, 0, stream>>>(cavg, linW[l], linb[l], xnbuf, ctrlI, co);

    const float* firPtr;
    if (l==0){
      for (int d=0;d<ND;d++)
        k_gemm<<<dim3(256/64, NN/64, 1), 256, 0, stream>>>(
          dims_in[d], 0, ch1W, 0, ch1b, 0, hbuf + (size_t)d*NN*256, 0, NN, 512, 256);
      firPtr = hbuf;
    } else if (l==1){
      k_gemm<<<dim3(128/64, NN/64, ND), 256, 0, stream>>>(
        oPrev, (long long)NN*256, ch2W, 0, ch2b, 0, hbuf, (long long)NN*128, NN, 256, 128);
      firPtr = hbuf;
    } else {
      firPtr = oPrev;
    }

    k_out<<<dim3(NN, ND), co, 0, stream>>>(firPtr, xnbuf, flagsA, ksv, oCur, co);

    gPrev = gCur; oPrev = oCur;
  }

  k_final<<<NN, 128, 0, stream>>>(oPrev, dimw, (float*)d_out);
}